// Round 1
// baseline (2857.230 us; speedup 1.0000x reference)
//
#include <hip/hip_runtime.h>
#include <hip/hip_bf16.h>

#define NN 100000
#define EE 1600000
#define D 128
// K concat dim = 3*D = 384

// ---------------------------------------------------------------------------
// SpMM scatter: y[src[e]] += val[e] * feat[dst[e]]   (y must be pre-zeroed)
// One 64-lane wave per edge; each lane handles 2 columns (float2 = 8B/lane).
// ---------------------------------------------------------------------------
__global__ __launch_bounds__(256) void spmm_atomic(
    const int* __restrict__ src, const int* __restrict__ dst,
    const float* __restrict__ val, const float* __restrict__ feat,
    float* __restrict__ out)
{
    const int tid  = blockIdx.x * 256 + threadIdx.x;
    const int e    = tid >> 6;       // one edge per wave
    const int lane = tid & 63;
    const int s = src[e];
    const int d = dst[e];
    const float v = val[e];
    const float2 f = reinterpret_cast<const float2*>(feat + (size_t)d * D)[lane];
    float* orow = out + (size_t)s * D + lane * 2;
    atomicAdd(orow,     v * f.x);
    atomicAdd(orow + 1, v * f.y);
}

// ---------------------------------------------------------------------------
// out[N,128] = concat(x,f1,f2)[N,384] @ W[128,384]^T + b[128]
// Tile: BM=64 rows, BN=128 (full), BK=32. 256 threads, thread tile 4 rows x
// 8 cols (two float4 col groups at tc*4 and 64+tc*4).
// LDS holds transposed h (hsT[kk][row]) and transposed W (ws[kk][col]) so the
// inner loop is 3x ds_read_b128 per 32 FMAs.
// ---------------------------------------------------------------------------
__global__ __launch_bounds__(256) void gemm_out(
    const float* __restrict__ x, const float* __restrict__ f1,
    const float* __restrict__ f2, const float* __restrict__ W,
    const float* __restrict__ b, float* __restrict__ out)
{
    __shared__ float hsT[32][68];   // [kk][row], 68*4=272B row pitch (16B-aligned)
    __shared__ float ws[32][128];   // [kk][col]

    const int t  = threadIdx.x;
    const int tc = t & 15;          // 0..15  -> col groups tc*4, 64+tc*4
    const int tr = t >> 4;          // 0..15  -> rows tr*4 .. tr*4+3
    const int rbase = blockIdx.x * 64;

    float acc[4][8];
    {
        const float4 b0 = *reinterpret_cast<const float4*>(b + tc * 4);
        const float4 b1 = *reinterpret_cast<const float4*>(b + 64 + tc * 4);
        #pragma unroll
        for (int i = 0; i < 4; ++i) {
            acc[i][0] = b0.x; acc[i][1] = b0.y; acc[i][2] = b0.z; acc[i][3] = b0.w;
            acc[i][4] = b1.x; acc[i][5] = b1.y; acc[i][6] = b1.z; acc[i][7] = b1.w;
        }
    }

    for (int c = 0; c < 12; ++c) {
        const float* hsrc = (c < 4) ? x : ((c < 8) ? f1 : f2);
        const int col0 = (c & 3) * 32;     // col offset within the 128-wide source
        const int k0   = c * 32;           // col offset within W rows

        // stage h tile: 64 rows x 32 k, transposed into hsT. 512 float4 loads.
        #pragma unroll
        for (int it = 0; it < 2; ++it) {
            const int f  = it * 256 + t;   // 0..511
            const int r  = f >> 3;         // 0..63
            const int kq = f & 7;          // 0..7
            const int rg = rbase + r;
            float4 hv = make_float4(0.f, 0.f, 0.f, 0.f);
            if (rg < NN)
                hv = *reinterpret_cast<const float4*>(hsrc + (size_t)rg * D + col0 + kq * 4);
            hsT[kq * 4 + 0][r] = hv.x;
            hsT[kq * 4 + 1][r] = hv.y;
            hsT[kq * 4 + 2][r] = hv.z;
            hsT[kq * 4 + 3][r] = hv.w;
        }
        // stage W tile: 128 cols x 32 k, transposed into ws. 1024 float4 loads.
        #pragma unroll
        for (int it = 0; it < 4; ++it) {
            const int f  = it * 256 + t;   // 0..1023
            const int j  = f >> 3;         // 0..127
            const int kq = f & 7;          // 0..7
            const float4 wv = *reinterpret_cast<const float4*>(W + (size_t)j * 384 + k0 + kq * 4);
            ws[kq * 4 + 0][j] = wv.x;
            ws[kq * 4 + 1][j] = wv.y;
            ws[kq * 4 + 2][j] = wv.z;
            ws[kq * 4 + 3][j] = wv.w;
        }
        __syncthreads();

        #pragma unroll
        for (int kk = 0; kk < 32; ++kk) {
            const float4 hv = *reinterpret_cast<const float4*>(&hsT[kk][tr * 4]);
            const float4 w0 = *reinterpret_cast<const float4*>(&ws[kk][tc * 4]);
            const float4 w1 = *reinterpret_cast<const float4*>(&ws[kk][64 + tc * 4]);
            const float hr[4] = {hv.x, hv.y, hv.z, hv.w};
            const float wc[8] = {w0.x, w0.y, w0.z, w0.w, w1.x, w1.y, w1.z, w1.w};
            #pragma unroll
            for (int i = 0; i < 4; ++i)
                #pragma unroll
                for (int jj = 0; jj < 8; ++jj)
                    acc[i][jj] = fmaf(hr[i], wc[jj], acc[i][jj]);
        }
        __syncthreads();
    }

    #pragma unroll
    for (int i = 0; i < 4; ++i) {
        const int rg = rbase + tr * 4 + i;
        if (rg < NN) {
            float4 o0, o1;
            o0.x = acc[i][0]; o0.y = acc[i][1]; o0.z = acc[i][2]; o0.w = acc[i][3];
            o1.x = acc[i][4]; o1.y = acc[i][5]; o1.z = acc[i][6]; o1.w = acc[i][7];
            *reinterpret_cast<float4*>(out + (size_t)rg * D + tc * 4)      = o0;
            *reinterpret_cast<float4*>(out + (size_t)rg * D + 64 + tc * 4) = o1;
        }
    }
}

extern "C" void kernel_launch(void* const* d_in, const int* in_sizes, int n_in,
                              void* d_out, int out_size, void* d_ws, size_t ws_size,
                              hipStream_t stream)
{
    const float* x    = (const float*)d_in[0];
    const int*   esrc = (const int*)  d_in[1];
    const int*   edst = (const int*)  d_in[2];
    const float* eval = (const float*)d_in[3];
    const float* W    = (const float*)d_in[4];
    const float* b    = (const float*)d_in[5];
    float* out = (float*)d_out;

    float* f1 = (float*)d_ws;
    float* f2 = f1 + (size_t)NN * D;
    const size_t fbytes = (size_t)NN * D * sizeof(float);

    hipMemsetAsync(f1, 0, 2 * fbytes, stream);

    // one wave per edge -> E/4 blocks of 256 threads
    spmm_atomic<<<EE / 4, 256, 0, stream>>>(esrc, edst, eval, x,  f1);
    spmm_atomic<<<EE / 4, 256, 0, stream>>>(esrc, edst, eval, f1, f2);

    gemm_out<<<(NN + 63) / 64, 256, 0, stream>>>(x, f1, f2, W, b, out);
}

// Round 2
// 826.550 us; speedup vs baseline: 3.4568x; 3.4568x over previous
//
#include <hip/hip_runtime.h>
#include <hip/hip_bf16.h>

#define NN 100000
#define EE 1600000
#define D 128
// concat dim = 3*D = 384

// ---------------------------------------------------------------------------
// CSR build step 1: histogram of src. rp[] must be pre-zeroed (NN+1 ints).
// ---------------------------------------------------------------------------
__global__ __launch_bounds__(256) void hist_kernel(
    const int* __restrict__ src, int* __restrict__ rp)
{
    const int e = blockIdx.x * 256 + threadIdx.x;
    atomicAdd(&rp[src[e]], 1);
}

// ---------------------------------------------------------------------------
// CSR build step 2: in-place exclusive scan of rp[0..NN-1]; rp[NN] = total.
// Single block, 1024 threads, strip-per-thread + LDS Hillis-Steele.
// Safe in-place: every thread touches only its own strip, and all strip reads
// complete before the first barrier of the LDS scan.
// ---------------------------------------------------------------------------
__global__ __launch_bounds__(1024) void scan_kernel(int* __restrict__ rp)
{
    const int STRIP = (NN + 1023) / 1024;  // 98
    const int tid = threadIdx.x;
    int base = tid * STRIP;
    int end  = base + STRIP;
    if (base > NN) base = NN;
    if (end  > NN) end  = NN;

    int s = 0;
    for (int i = base; i < end; ++i) s += rp[i];

    __shared__ int tmp[1024];
    tmp[tid] = s;
    __syncthreads();
    for (int off = 1; off < 1024; off <<= 1) {
        const int v = (tid >= off) ? tmp[tid - off] : 0;
        __syncthreads();
        tmp[tid] += v;
        __syncthreads();
    }
    int run = tmp[tid] - s;   // exclusive prefix of this strip
    for (int i = base; i < end; ++i) { const int c = rp[i]; rp[i] = run; run += c; }
    if (tid == 1023) rp[NN] = run;
}

// ---------------------------------------------------------------------------
// CSR build step 3: permute edges into CSR slots. atomicAdd on rp[s] returns
// the slot AND leaves rp[s] == end-of-row-s (so row i = [rp[i-1], rp[i])).
// csr[] packs {dst, bitcast(val)} so the SpMM does one 8B load per edge.
// ---------------------------------------------------------------------------
__global__ __launch_bounds__(256) void permute_kernel(
    const int* __restrict__ src, const int* __restrict__ dst,
    const float* __restrict__ val, int* __restrict__ rp, int2* __restrict__ csr)
{
    const int e = blockIdx.x * 256 + threadIdx.x;
    const int s = src[e];
    const int pos = atomicAdd(&rp[s], 1);
    csr[pos] = make_int2(dst[e], __float_as_int(val[e]));
}

// ---------------------------------------------------------------------------
// SpMM (CSR): one 64-lane wave per row; lane holds float2 (cols lane*2,+1).
// Per edge: one broadcast int2 load + one coalesced 512B feat-row gather.
// No atomics; all rows written (empty rows -> 0), so no output pre-zeroing.
// ---------------------------------------------------------------------------
__global__ __launch_bounds__(256) void spmm_csr(
    const int* __restrict__ rp, const int2* __restrict__ csr,
    const float* __restrict__ feat, float* __restrict__ out)
{
    const int tid  = blockIdx.x * 256 + threadIdx.x;
    const int row  = tid >> 6;
    const int lane = tid & 63;
    if (row >= NN) return;
    const int start = (row == 0) ? 0 : rp[row - 1];
    const int end   = rp[row];

    const float2* feat2 = reinterpret_cast<const float2*>(feat);
    float2 a0 = make_float2(0.f, 0.f), a1 = make_float2(0.f, 0.f);

    int p = start;
    for (; p + 2 <= end; p += 2) {
        const int2 e0 = csr[p];
        const int2 e1 = csr[p + 1];
        const float v0 = __int_as_float(e0.y);
        const float v1 = __int_as_float(e1.y);
        const float2 f0 = feat2[(size_t)e0.x * 64 + lane];
        const float2 f1 = feat2[(size_t)e1.x * 64 + lane];
        a0.x = fmaf(v0, f0.x, a0.x); a0.y = fmaf(v0, f0.y, a0.y);
        a1.x = fmaf(v1, f1.x, a1.x); a1.y = fmaf(v1, f1.y, a1.y);
    }
    if (p < end) {
        const int2 e0 = csr[p];
        const float v0 = __int_as_float(e0.y);
        const float2 f0 = feat2[(size_t)e0.x * 64 + lane];
        a0.x = fmaf(v0, f0.x, a0.x); a0.y = fmaf(v0, f0.y, a0.y);
    }
    float2 r; r.x = a0.x + a1.x; r.y = a0.y + a1.y;
    reinterpret_cast<float2*>(out)[(size_t)row * 64 + lane] = r;
}

// ---------------------------------------------------------------------------
// out[N,128] = concat(x,f1,f2)[N,384] @ W[128,384]^T + b[128]
// BM=64, BN=128, BK=32; 256 threads, 4x8 register tile; LDS-transposed tiles.
// ---------------------------------------------------------------------------
__global__ __launch_bounds__(256) void gemm_out(
    const float* __restrict__ x, const float* __restrict__ f1,
    const float* __restrict__ f2, const float* __restrict__ W,
    const float* __restrict__ b, float* __restrict__ out)
{
    __shared__ float hsT[32][68];
    __shared__ float ws[32][128];

    const int t  = threadIdx.x;
    const int tc = t & 15;
    const int tr = t >> 4;
    const int rbase = blockIdx.x * 64;

    float acc[4][8];
    {
        const float4 b0 = *reinterpret_cast<const float4*>(b + tc * 4);
        const float4 b1 = *reinterpret_cast<const float4*>(b + 64 + tc * 4);
        #pragma unroll
        for (int i = 0; i < 4; ++i) {
            acc[i][0] = b0.x; acc[i][1] = b0.y; acc[i][2] = b0.z; acc[i][3] = b0.w;
            acc[i][4] = b1.x; acc[i][5] = b1.y; acc[i][6] = b1.z; acc[i][7] = b1.w;
        }
    }

    for (int c = 0; c < 12; ++c) {
        const float* hsrc = (c < 4) ? x : ((c < 8) ? f1 : f2);
        const int col0 = (c & 3) * 32;
        const int k0   = c * 32;

        #pragma unroll
        for (int it = 0; it < 2; ++it) {
            const int f  = it * 256 + t;
            const int r  = f >> 3;
            const int kq = f & 7;
            const int rg = rbase + r;
            float4 hv = make_float4(0.f, 0.f, 0.f, 0.f);
            if (rg < NN)
                hv = *reinterpret_cast<const float4*>(hsrc + (size_t)rg * D + col0 + kq * 4);
            hsT[kq * 4 + 0][r] = hv.x;
            hsT[kq * 4 + 1][r] = hv.y;
            hsT[kq * 4 + 2][r] = hv.z;
            hsT[kq * 4 + 3][r] = hv.w;
        }
        #pragma unroll
        for (int it = 0; it < 4; ++it) {
            const int f  = it * 256 + t;
            const int j  = f >> 3;
            const int kq = f & 7;
            const float4 wv = *reinterpret_cast<const float4*>(W + (size_t)j * 384 + k0 + kq * 4);
            ws[kq * 4 + 0][j] = wv.x;
            ws[kq * 4 + 1][j] = wv.y;
            ws[kq * 4 + 2][j] = wv.z;
            ws[kq * 4 + 3][j] = wv.w;
        }
        __syncthreads();

        #pragma unroll
        for (int kk = 0; kk < 32; ++kk) {
            const float4 hv = *reinterpret_cast<const float4*>(&hsT[kk][tr * 4]);
            const float4 w0 = *reinterpret_cast<const float4*>(&ws[kk][tc * 4]);
            const float4 w1 = *reinterpret_cast<const float4*>(&ws[kk][64 + tc * 4]);
            const float hr[4] = {hv.x, hv.y, hv.z, hv.w};
            const float wc[8] = {w0.x, w0.y, w0.z, w0.w, w1.x, w1.y, w1.z, w1.w};
            #pragma unroll
            for (int i = 0; i < 4; ++i)
                #pragma unroll
                for (int jj = 0; jj < 8; ++jj)
                    acc[i][jj] = fmaf(hr[i], wc[jj], acc[i][jj]);
        }
        __syncthreads();
    }

    #pragma unroll
    for (int i = 0; i < 4; ++i) {
        const int rg = rbase + tr * 4 + i;
        if (rg < NN) {
            float4 o0, o1;
            o0.x = acc[i][0]; o0.y = acc[i][1]; o0.z = acc[i][2]; o0.w = acc[i][3];
            o1.x = acc[i][4]; o1.y = acc[i][5]; o1.z = acc[i][6]; o1.w = acc[i][7];
            *reinterpret_cast<float4*>(out + (size_t)rg * D + tc * 4)      = o0;
            *reinterpret_cast<float4*>(out + (size_t)rg * D + 64 + tc * 4) = o1;
        }
    }
}

extern "C" void kernel_launch(void* const* d_in, const int* in_sizes, int n_in,
                              void* d_out, int out_size, void* d_ws, size_t ws_size,
                              hipStream_t stream)
{
    const float* x    = (const float*)d_in[0];
    const int*   esrc = (const int*)  d_in[1];
    const int*   edst = (const int*)  d_in[2];
    const float* eval = (const float*)d_in[3];
    const float* W    = (const float*)d_in[4];
    const float* b    = (const float*)d_in[5];
    float* out = (float*)d_out;

    char* ws = (char*)d_ws;
    float* f1  = (float*)(ws);                                   // 51.2 MB
    float* f2  = (float*)(ws + (size_t)NN * D * 4);              // 51.2 MB
    int2*  csr = (int2*) (ws + (size_t)2 * NN * D * 4);          // 12.8 MB (8B-aligned)
    int*   rp  = (int*)  (ws + (size_t)2 * NN * D * 4 + (size_t)EE * 8);  // 400 KB

    hipMemsetAsync(rp, 0, (NN + 1) * sizeof(int), stream);

    hist_kernel   <<<EE / 256, 256, 0, stream>>>(esrc, rp);
    scan_kernel   <<<1, 1024, 0, stream>>>(rp);
    permute_kernel<<<EE / 256, 256, 0, stream>>>(esrc, edst, eval, rp, csr);

    spmm_csr<<<NN / 4, 256, 0, stream>>>(rp, csr, x,  f1);
    spmm_csr<<<NN / 4, 256, 0, stream>>>(rp, csr, f1, f2);

    gemm_out<<<(NN + 63) / 64, 256, 0, stream>>>(x, f1, f2, W, b, out);
}

// Round 3
// 617.703 us; speedup vs baseline: 4.6256x; 1.3381x over previous
//
#include <hip/hip_runtime.h>
#include <hip/hip_bf16.h>

#define NN 100000
#define EE 1600000
#define D 128

typedef __attribute__((ext_vector_type(4))) float f32x4;
typedef __attribute__((ext_vector_type(8))) short s16x8;   // 8 bf16 in 4 VGPRs

__device__ inline ushort f2bf(float f) {       // f32 -> bf16 RNE
    uint b = __float_as_uint(f);
    return (ushort)((b + 0x7fffu + ((b >> 16) & 1u)) >> 16);
}
__device__ inline float bflo(uint g) { return __uint_as_float(g << 16); }
__device__ inline float bfhi(uint g) { return __uint_as_float(g & 0xffff0000u); }

// ---------------------------------------------------------------------------
// f32 -> bf16 convert, 4 elems/thread. n4 = n/4.
// ---------------------------------------------------------------------------
__global__ __launch_bounds__(256) void cvt_bf16(
    const float* __restrict__ in, ushort* __restrict__ out, int n4)
{
    const int i = blockIdx.x * 256 + threadIdx.x;
    if (i >= n4) return;
    const float4 v = reinterpret_cast<const float4*>(in)[i];
    ushort4 o;
    o.x = f2bf(v.x); o.y = f2bf(v.y); o.z = f2bf(v.z); o.w = f2bf(v.w);
    reinterpret_cast<ushort4*>(out)[i] = o;
}

// ---------------------------------------------------------------------------
// CSR build: histogram -> scan -> permute (same as R1, verified).
// ---------------------------------------------------------------------------
__global__ __launch_bounds__(256) void hist_kernel(
    const int* __restrict__ src, int* __restrict__ rp)
{
    const int e = blockIdx.x * 256 + threadIdx.x;
    atomicAdd(&rp[src[e]], 1);
}

__global__ __launch_bounds__(1024) void scan_kernel(int* __restrict__ rp)
{
    const int STRIP = (NN + 1023) / 1024;
    const int tid = threadIdx.x;
    int base = tid * STRIP, end = base + STRIP;
    if (base > NN) base = NN;
    if (end  > NN) end  = NN;
    int s = 0;
    for (int i = base; i < end; ++i) s += rp[i];
    __shared__ int tmp[1024];
    tmp[tid] = s;
    __syncthreads();
    for (int off = 1; off < 1024; off <<= 1) {
        const int v = (tid >= off) ? tmp[tid - off] : 0;
        __syncthreads();
        tmp[tid] += v;
        __syncthreads();
    }
    int run = tmp[tid] - s;
    for (int i = base; i < end; ++i) { const int c = rp[i]; rp[i] = run; run += c; }
    if (tid == 1023) rp[NN] = run;
}

__global__ __launch_bounds__(256) void permute_kernel(
    const int* __restrict__ src, const int* __restrict__ dst,
    const float* __restrict__ val, int* __restrict__ rp, int2* __restrict__ csr)
{
    const int e = blockIdx.x * 256 + threadIdx.x;
    const int s = src[e];
    const int pos = atomicAdd(&rp[s], 1);
    csr[pos] = make_int2(dst[e], __float_as_int(val[e]));
}

// ---------------------------------------------------------------------------
// SpMM (CSR, bf16 feat): one wave per row; lane holds cols 2*lane, 2*lane+1
// (one dword of bf16x2 per gather). f32 accumulate, bf16 output. 4-deep MLP.
// ---------------------------------------------------------------------------
__global__ __launch_bounds__(256) void spmm_csr_bf16(
    const int* __restrict__ rp, const int2* __restrict__ csr,
    const ushort* __restrict__ featb, ushort* __restrict__ outb)
{
    const int tid  = blockIdx.x * 256 + threadIdx.x;
    const int row  = tid >> 6;
    const int lane = tid & 63;
    const int start = (row == 0) ? 0 : rp[row - 1];
    const int end   = rp[row];

    const uint* f = reinterpret_cast<const uint*>(featb);
    float ax0 = 0.f, ay0 = 0.f, ax1 = 0.f, ay1 = 0.f;
    float ax2 = 0.f, ay2 = 0.f, ax3 = 0.f, ay3 = 0.f;

    int p = start;
    for (; p + 4 <= end; p += 4) {
        const int2 e0 = csr[p],     e1 = csr[p + 1];
        const int2 e2 = csr[p + 2], e3 = csr[p + 3];
        const uint g0 = f[(size_t)e0.x * 64 + lane];
        const uint g1 = f[(size_t)e1.x * 64 + lane];
        const uint g2 = f[(size_t)e2.x * 64 + lane];
        const uint g3 = f[(size_t)e3.x * 64 + lane];
        const float v0 = __int_as_float(e0.y), v1 = __int_as_float(e1.y);
        const float v2 = __int_as_float(e2.y), v3 = __int_as_float(e3.y);
        ax0 = fmaf(v0, bflo(g0), ax0); ay0 = fmaf(v0, bfhi(g0), ay0);
        ax1 = fmaf(v1, bflo(g1), ax1); ay1 = fmaf(v1, bfhi(g1), ay1);
        ax2 = fmaf(v2, bflo(g2), ax2); ay2 = fmaf(v2, bfhi(g2), ay2);
        ax3 = fmaf(v3, bflo(g3), ax3); ay3 = fmaf(v3, bfhi(g3), ay3);
    }
    for (; p < end; ++p) {
        const int2 e0 = csr[p];
        const uint g0 = f[(size_t)e0.x * 64 + lane];
        const float v0 = __int_as_float(e0.y);
        ax0 = fmaf(v0, bflo(g0), ax0); ay0 = fmaf(v0, bfhi(g0), ay0);
    }
    const float rx = (ax0 + ax1) + (ax2 + ax3);
    const float ry = (ay0 + ay1) + (ay2 + ay3);
    reinterpret_cast<uint*>(outb)[(size_t)row * 64 + lane] =
        ((uint)f2bf(ry) << 16) | (uint)f2bf(rx);
}

// ---------------------------------------------------------------------------
// out[N,128] = concat(xb,f1b,f2b)[N,384](bf16) @ Wb[128,384](bf16)^T + b
// MFMA 16x16x32_bf16. BM=64, BK=64, 256 threads = 4 waves; wave w owns rows
// w*16..w*16+15, all 128 cols (8 col-tiles). LDS tiles XOR-swizzled (T2/G4):
// 16B chunk index ^= (row&7), so staging writes and frag reads are ~2-way.
// A/B frag: lane holds 8 contiguous K elems at k=(lane>>4)*8; C/D:
// col=lane&15, row=(lane>>4)*4+reg (m89-verified mapping).
// ---------------------------------------------------------------------------
__global__ __launch_bounds__(256) void gemm_mfma(
    const ushort* __restrict__ xb, const ushort* __restrict__ f1b,
    const ushort* __restrict__ f2b, const ushort* __restrict__ Wb,
    const float* __restrict__ b, float* __restrict__ out)
{
    __shared__ ushort As[64 * 64];    // [row][chunk^ (row&7)], 8 chunks of 8 ushort
    __shared__ ushort Ws[128 * 64];

    const int t    = threadIdx.x;
    const int wave = t >> 6;
    const int lane = t & 63;
    const int lr   = lane & 15;       // row (A) / col (B) within 16
    const int lg   = lane >> 4;       // k-group: k = lg*8 + i
    const int wr   = wave * 16;
    const int rbase = blockIdx.x * 64;

    f32x4 acc[8];
    #pragma unroll
    for (int j = 0; j < 8; ++j) {
        const float bv = b[j * 16 + lr];
        acc[j] = (f32x4){bv, bv, bv, bv};
    }

    for (int c = 0; c < 6; ++c) {
        const ushort* src = (c < 2) ? xb : ((c < 4) ? f1b : f2b);
        const int col0 = (c & 1) * 64;    // within the 128-wide source
        const int k0w  = c * 64;          // within W's 384-wide K

        // stage A: 64 rows x 64 k bf16 = 512 x 16B chunks
        #pragma unroll
        for (int it = 0; it < 2; ++it) {
            const int fidx = it * 256 + t;
            const int r = fidx >> 3, seg = fidx & 7;
            const int rg = rbase + r;
            s16x8 v = (s16x8)0;
            if (rg < NN)
                v = *reinterpret_cast<const s16x8*>(src + (size_t)rg * 128 + col0 + seg * 8);
            *reinterpret_cast<s16x8*>(&As[r * 64 + ((seg ^ (r & 7)) * 8)]) = v;
        }
        // stage W: 128 cols x 64 k bf16 = 1024 x 16B chunks
        #pragma unroll
        for (int it = 0; it < 4; ++it) {
            const int fidx = it * 256 + t;
            const int j = fidx >> 3, seg = fidx & 7;
            const s16x8 v = *reinterpret_cast<const s16x8*>(Wb + (size_t)j * 384 + k0w + seg * 8);
            *reinterpret_cast<s16x8*>(&Ws[j * 64 + ((seg ^ (j & 7)) * 8)]) = v;
        }
        __syncthreads();

        #pragma unroll
        for (int kk = 0; kk < 2; ++kk) {
            const int ar = wr + lr;
            const int ach = (kk * 4 + lg) ^ (ar & 7);
            const s16x8 a = *reinterpret_cast<const s16x8*>(&As[ar * 64 + ach * 8]);
            #pragma unroll
            for (int j = 0; j < 8; ++j) {
                const int bcol = j * 16 + lr;
                const int bch  = (kk * 4 + lg) ^ (bcol & 7);
                const s16x8 bf = *reinterpret_cast<const s16x8*>(&Ws[bcol * 64 + bch * 8]);
                acc[j] = __builtin_amdgcn_mfma_f32_16x16x32_bf16(a, bf, acc[j], 0, 0, 0);
            }
        }
        __syncthreads();
    }

    #pragma unroll
    for (int j = 0; j < 8; ++j) {
        #pragma unroll
        for (int j2 = 0; j2 < 4; ++j2) {
            const int rg = rbase + wr + lg * 4 + j2;
            if (rg < NN)
                out[(size_t)rg * 128 + j * 16 + lr] = acc[j][j2];
        }
    }
}

extern "C" void kernel_launch(void* const* d_in, const int* in_sizes, int n_in,
                              void* d_out, int out_size, void* d_ws, size_t ws_size,
                              hipStream_t stream)
{
    const float* x    = (const float*)d_in[0];
    const int*   esrc = (const int*)  d_in[1];
    const int*   edst = (const int*)  d_in[2];
    const float* eval = (const float*)d_in[3];
    const float* W    = (const float*)d_in[4];
    const float* b    = (const float*)d_in[5];
    float* out = (float*)d_out;

    char* ws = (char*)d_ws;
    const size_t FB = (size_t)NN * D * 2;          // 25,600,000 B per bf16 feat
    ushort* xb  = (ushort*)(ws);
    ushort* f1b = (ushort*)(ws + FB);
    ushort* f2b = (ushort*)(ws + 2 * FB);
    ushort* Wb  = (ushort*)(ws + 3 * FB);          // 98,304 B
    int2*   csr = (int2*)  (ws + 3 * FB + 98304);  // 12.8 MB
    int*    rp  = (int*)   (ws + 3 * FB + 98304 + (size_t)EE * 8);

    hipMemsetAsync(rp, 0, (NN + 1) * sizeof(int), stream);

    cvt_bf16<<<(NN * D / 4 + 255) / 256, 256, 0, stream>>>(x, xb, NN * D / 4);
    cvt_bf16<<<(128 * 384 / 4 + 255) / 256, 256, 0, stream>>>(W, Wb, 128 * 384 / 4);

    hist_kernel   <<<EE / 256, 256, 0, stream>>>(esrc, rp);
    scan_kernel   <<<1, 1024, 0, stream>>>(rp);
    permute_kernel<<<EE / 256, 256, 0, stream>>>(esrc, edst, eval, rp, csr);

    spmm_csr_bf16<<<NN / 4, 256, 0, stream>>>(rp, csr, xb,  f1b);
    spmm_csr_bf16<<<NN / 4, 256, 0, stream>>>(rp, csr, f1b, f2b);

    gemm_mfma<<<(NN + 63) / 64, 256, 0, stream>>>(xb, f1b, f2b, Wb, b, out);
}

// Round 4
// 413.901 us; speedup vs baseline: 6.9032x; 1.4924x over previous
//
#include <hip/hip_runtime.h>
#include <hip/hip_bf16.h>

#define NN 100000
#define EE 1600000
#define D 128
#define SCAN_TILE 512
#define NB1 ((NN + SCAN_TILE - 1) / SCAN_TILE)   // 196

typedef __attribute__((ext_vector_type(4))) float f32x4;
typedef __attribute__((ext_vector_type(8))) short s16x8;   // 8 bf16 in 4 VGPRs

__device__ inline ushort f2bf(float f) {       // f32 -> bf16 RNE
    uint b = __float_as_uint(f);
    return (ushort)((b + 0x7fffu + ((b >> 16) & 1u)) >> 16);
}
__device__ inline float bflo(uint g) { return __uint_as_float(g << 16); }
__device__ inline float bfhi(uint g) { return __uint_as_float(g & 0xffff0000u); }

// ---------------------------------------------------------------------------
// f32 -> bf16 convert, 4 elems/thread. n4 = n/4.
// ---------------------------------------------------------------------------
__global__ __launch_bounds__(256) void cvt_bf16(
    const float* __restrict__ in, ushort* __restrict__ out, int n4)
{
    const int i = blockIdx.x * 256 + threadIdx.x;
    if (i >= n4) return;
    const float4 v = reinterpret_cast<const float4*>(in)[i];
    ushort4 o;
    o.x = f2bf(v.x); o.y = f2bf(v.y); o.z = f2bf(v.z); o.w = f2bf(v.w);
    reinterpret_cast<ushort4*>(out)[i] = o;
}

// ---------------------------------------------------------------------------
// CSR build 1: histogram of src + per-edge rank (slot within its row).
// rp[] pre-zeroed. rank[e] = old count -> permute needs no atomics.
// ---------------------------------------------------------------------------
__global__ __launch_bounds__(256) void hist_kernel(
    const int* __restrict__ src, int* __restrict__ rp, int* __restrict__ rank)
{
    const int e = blockIdx.x * 256 + threadIdx.x;
    rank[e] = atomicAdd(&rp[src[e]], 1);
}

// ---------------------------------------------------------------------------
// CSR build 2: exclusive scan of rp[0..NN-1], 3-level multi-block.
// ---------------------------------------------------------------------------
__global__ __launch_bounds__(256) void scan1_kernel(
    int* __restrict__ rp, int* __restrict__ part)
{
    const int t = threadIdx.x;
    const int base = blockIdx.x * SCAN_TILE + t * 2;
    int c0 = 0, c1 = 0;
    if (base < NN)     c0 = rp[base];
    if (base + 1 < NN) c1 = rp[base + 1];
    const int s = c0 + c1;
    __shared__ int tmp[256];
    tmp[t] = s;
    __syncthreads();
    for (int off = 1; off < 256; off <<= 1) {
        const int v = (t >= off) ? tmp[t - off] : 0;
        __syncthreads();
        tmp[t] += v;
        __syncthreads();
    }
    const int excl = tmp[t] - s;         // exclusive prefix within block
    if (base < NN)     rp[base]     = excl;
    if (base + 1 < NN) rp[base + 1] = excl + c0;
    if (t == 255) part[blockIdx.x] = tmp[255];
}

__global__ __launch_bounds__(256) void scan2_kernel(int* __restrict__ part)
{
    const int t = threadIdx.x;
    const int s = (t < NB1) ? part[t] : 0;
    __shared__ int tmp[256];
    tmp[t] = s;
    __syncthreads();
    for (int off = 1; off < 256; off <<= 1) {
        const int v = (t >= off) ? tmp[t - off] : 0;
        __syncthreads();
        tmp[t] += v;
        __syncthreads();
    }
    if (t < NB1) part[t] = tmp[t] - s;   // exclusive
}

__global__ __launch_bounds__(256) void scan3_kernel(
    int* __restrict__ rp, const int* __restrict__ part)
{
    const int t = threadIdx.x;
    const int base = blockIdx.x * SCAN_TILE + t * 2;
    const int p = part[blockIdx.x];
    if (base < NN)     rp[base]     += p;
    if (base + 1 < NN) rp[base + 1] += p;
    if (blockIdx.x == 0 && t == 0) rp[NN] = EE;
}

// ---------------------------------------------------------------------------
// CSR build 3: permute edges into slots (no atomics; rp stays pristine).
// ---------------------------------------------------------------------------
__global__ __launch_bounds__(256) void permute_kernel(
    const int* __restrict__ src, const int* __restrict__ dst,
    const float* __restrict__ val, const int* __restrict__ rp,
    const int* __restrict__ rank, int2* __restrict__ csr)
{
    const int e = blockIdx.x * 256 + threadIdx.x;
    const int pos = rp[src[e]] + rank[e];
    csr[pos] = make_int2(dst[e], __float_as_int(val[e]));
}

// ---------------------------------------------------------------------------
// SpMM (CSR, bf16 feat): one wave per row; lane holds cols 2*lane, 2*lane+1
// (one dword of bf16x2 per gather). f32 accumulate, bf16 output. 4-deep MLP.
// ---------------------------------------------------------------------------
__global__ __launch_bounds__(256) void spmm_csr_bf16(
    const int* __restrict__ rp, const int2* __restrict__ csr,
    const ushort* __restrict__ featb, ushort* __restrict__ outb)
{
    const int tid  = blockIdx.x * 256 + threadIdx.x;
    const int row  = tid >> 6;
    const int lane = tid & 63;
    const int start = rp[row];
    const int end   = rp[row + 1];

    const uint* f = reinterpret_cast<const uint*>(featb);
    float ax0 = 0.f, ay0 = 0.f, ax1 = 0.f, ay1 = 0.f;
    float ax2 = 0.f, ay2 = 0.f, ax3 = 0.f, ay3 = 0.f;

    int p = start;
    for (; p + 4 <= end; p += 4) {
        const int2 e0 = csr[p],     e1 = csr[p + 1];
        const int2 e2 = csr[p + 2], e3 = csr[p + 3];
        const uint g0 = f[(size_t)e0.x * 64 + lane];
        const uint g1 = f[(size_t)e1.x * 64 + lane];
        const uint g2 = f[(size_t)e2.x * 64 + lane];
        const uint g3 = f[(size_t)e3.x * 64 + lane];
        const float v0 = __int_as_float(e0.y), v1 = __int_as_float(e1.y);
        const float v2 = __int_as_float(e2.y), v3 = __int_as_float(e3.y);
        ax0 = fmaf(v0, bflo(g0), ax0); ay0 = fmaf(v0, bfhi(g0), ay0);
        ax1 = fmaf(v1, bflo(g1), ax1); ay1 = fmaf(v1, bfhi(g1), ay1);
        ax2 = fmaf(v2, bflo(g2), ax2); ay2 = fmaf(v2, bfhi(g2), ay2);
        ax3 = fmaf(v3, bflo(g3), ax3); ay3 = fmaf(v3, bfhi(g3), ay3);
    }
    for (; p < end; ++p) {
        const int2 e0 = csr[p];
        const uint g0 = f[(size_t)e0.x * 64 + lane];
        const float v0 = __int_as_float(e0.y);
        ax0 = fmaf(v0, bflo(g0), ax0); ay0 = fmaf(v0, bfhi(g0), ay0);
    }
    const float rx = (ax0 + ax1) + (ax2 + ax3);
    const float ry = (ay0 + ay1) + (ay2 + ay3);
    reinterpret_cast<uint*>(outb)[(size_t)row * 64 + lane] =
        ((uint)f2bf(ry) << 16) | (uint)f2bf(rx);
}

// ---------------------------------------------------------------------------
// out[N,128] = concat(xb,f1b,f2b)[N,384](bf16) @ Wb[128,384](bf16)^T + b
// MFMA 16x16x32_bf16. BM=64, BK=64, 4 waves; XOR-swizzled LDS.
// ---------------------------------------------------------------------------
__global__ __launch_bounds__(256) void gemm_mfma(
    const ushort* __restrict__ xb, const ushort* __restrict__ f1b,
    const ushort* __restrict__ f2b, const ushort* __restrict__ Wb,
    const float* __restrict__ b, float* __restrict__ out)
{
    __shared__ ushort As[64 * 64];
    __shared__ ushort Ws[128 * 64];

    const int t    = threadIdx.x;
    const int wave = t >> 6;
    const int lane = t & 63;
    const int lr   = lane & 15;
    const int lg   = lane >> 4;
    const int wr   = wave * 16;
    const int rbase = blockIdx.x * 64;

    f32x4 acc[8];
    #pragma unroll
    for (int j = 0; j < 8; ++j) {
        const float bv = b[j * 16 + lr];
        acc[j] = (f32x4){bv, bv, bv, bv};
    }

    for (int c = 0; c < 6; ++c) {
        const ushort* src = (c < 2) ? xb : ((c < 4) ? f1b : f2b);
        const int col0 = (c & 1) * 64;
        const int k0w  = c * 64;

        #pragma unroll
        for (int it = 0; it < 2; ++it) {
            const int fidx = it * 256 + t;
            const int r = fidx >> 3, seg = fidx & 7;
            const int rg = rbase + r;
            s16x8 v = (s16x8)0;
            if (rg < NN)
                v = *reinterpret_cast<const s16x8*>(src + (size_t)rg * 128 + col0 + seg * 8);
            *reinterpret_cast<s16x8*>(&As[r * 64 + ((seg ^ (r & 7)) * 8)]) = v;
        }
        #pragma unroll
        for (int it = 0; it < 4; ++it) {
            const int fidx = it * 256 + t;
            const int j = fidx >> 3, seg = fidx & 7;
            const s16x8 v = *reinterpret_cast<const s16x8*>(Wb + (size_t)j * 384 + k0w + seg * 8);
            *reinterpret_cast<s16x8*>(&Ws[j * 64 + ((seg ^ (j & 7)) * 8)]) = v;
        }
        __syncthreads();

        #pragma unroll
        for (int kk = 0; kk < 2; ++kk) {
            const int ar = wr + lr;
            const int ach = (kk * 4 + lg) ^ (ar & 7);
            const s16x8 a = *reinterpret_cast<const s16x8*>(&As[ar * 64 + ach * 8]);
            #pragma unroll
            for (int j = 0; j < 8; ++j) {
                const int bcol = j * 16 + lr;
                const int bch  = (kk * 4 + lg) ^ (bcol & 7);
                const s16x8 bf = *reinterpret_cast<const s16x8*>(&Ws[bcol * 64 + bch * 8]);
                acc[j] = __builtin_amdgcn_mfma_f32_16x16x32_bf16(a, bf, acc[j], 0, 0, 0);
            }
        }
        __syncthreads();
    }

    #pragma unroll
    for (int j = 0; j < 8; ++j) {
        #pragma unroll
        for (int j2 = 0; j2 < 4; ++j2) {
            const int rg = rbase + wr + lg * 4 + j2;
            if (rg < NN)
                out[(size_t)rg * 128 + j * 16 + lr] = acc[j][j2];
        }
    }
}

extern "C" void kernel_launch(void* const* d_in, const int* in_sizes, int n_in,
                              void* d_out, int out_size, void* d_ws, size_t ws_size,
                              hipStream_t stream)
{
    const float* x    = (const float*)d_in[0];
    const int*   esrc = (const int*)  d_in[1];
    const int*   edst = (const int*)  d_in[2];
    const float* eval = (const float*)d_in[3];
    const float* W    = (const float*)d_in[4];
    const float* b    = (const float*)d_in[5];
    float* out = (float*)d_out;

    char* ws = (char*)d_ws;
    const size_t FB = (size_t)NN * D * 2;               // 25,600,000 B
    ushort* xb   = (ushort*)(ws);
    ushort* f1b  = (ushort*)(ws + FB);
    ushort* f2b  = (ushort*)(ws + 2 * FB);
    ushort* Wb   = (ushort*)(ws + 3 * FB);              // 98,304 B
    int2*   csr  = (int2*)  (ws + 3 * FB + 98304);      // 12,800,000 B
    int*    rank = (int*)   (ws + 3 * FB + 98304 + (size_t)EE * 8);       // 6.4 MB
    int*    rp   = (int*)   (ws + 3 * FB + 98304 + (size_t)EE * 8 + (size_t)EE * 4); // 400,016 B
    int*    part = (int*)   (ws + 3 * FB + 98304 + (size_t)EE * 8 + (size_t)EE * 4 + 400016);

    hipMemsetAsync(rp, 0, (NN + 1) * sizeof(int), stream);

    cvt_bf16<<<(NN * D / 4 + 255) / 256, 256, 0, stream>>>(x, xb, NN * D / 4);
    cvt_bf16<<<(128 * 384 / 4 + 255) / 256, 256, 0, stream>>>(W, Wb, 128 * 384 / 4);

    hist_kernel <<<EE / 256, 256, 0, stream>>>(esrc, rp, rank);
    scan1_kernel<<<NB1, 256, 0, stream>>>(rp, part);
    scan2_kernel<<<1, 256, 0, stream>>>(part);
    scan3_kernel<<<NB1, 256, 0, stream>>>(rp, part);
    permute_kernel<<<EE / 256, 256, 0, stream>>>(esrc, edst, eval, rp, rank, csr);

    spmm_csr_bf16<<<NN / 4, 256, 0, stream>>>(rp, csr, xb,  f1b);
    spmm_csr_bf16<<<NN / 4, 256, 0, stream>>>(rp, csr, f1b, f2b);

    gemm_mfma<<<(NN + 63) / 64, 256, 0, stream>>>(xb, f1b, f2b, Wb, b, out);
}

// Round 8
// 388.139 us; speedup vs baseline: 7.3614x; 1.0664x over previous
//
#include <hip/hip_runtime.h>
#include <hip/hip_bf16.h>

#define NN 100000
#define EE 1600000
#define D 128
#define SCAN_TILE 512
#define NB1 ((NN + SCAN_TILE - 1) / SCAN_TILE)   // 196

typedef __attribute__((ext_vector_type(4))) float f32x4;
typedef __attribute__((ext_vector_type(8))) short s16x8;   // 8 bf16 in 4 VGPRs

__device__ inline ushort f2bf(float f) {       // f32 -> bf16 RNE
    uint b = __float_as_uint(f);
    return (ushort)((b + 0x7fffu + ((b >> 16) & 1u)) >> 16);
}
__device__ inline float bflo(uint g) { return __uint_as_float(g << 16); }
__device__ inline float bfhi(uint g) { return __uint_as_float(g & 0xffff0000u); }

// ---------------------------------------------------------------------------
// f32 -> bf16 convert, 4 elems/thread. n4 = n/4.
// ---------------------------------------------------------------------------
__global__ __launch_bounds__(256) void cvt_bf16(
    const float* __restrict__ in, ushort* __restrict__ out, int n4)
{
    const int i = blockIdx.x * 256 + threadIdx.x;
    if (i >= n4) return;
    const float4 v = reinterpret_cast<const float4*>(in)[i];
    ushort4 o;
    o.x = f2bf(v.x); o.y = f2bf(v.y); o.z = f2bf(v.z); o.w = f2bf(v.w);
    reinterpret_cast<ushort4*>(out)[i] = o;
}

// ---------------------------------------------------------------------------
// CSR build 1: histogram of src + per-edge rank. rp[] pre-zeroed.
// ---------------------------------------------------------------------------
__global__ __launch_bounds__(256) void hist_kernel(
    const int* __restrict__ src, int* __restrict__ rp, int* __restrict__ rank)
{
    const int e = blockIdx.x * 256 + threadIdx.x;
    rank[e] = atomicAdd(&rp[src[e]], 1);
}

// ---------------------------------------------------------------------------
// CSR build 2: two-level scan. After scan1+scan2:
//   global_offset(i) = rp[i] + part[i >> 9]   (consumers add part themselves)
// ---------------------------------------------------------------------------
__global__ __launch_bounds__(256) void scan1_kernel(
    int* __restrict__ rp, int* __restrict__ part)
{
    const int t = threadIdx.x;
    const int base = blockIdx.x * SCAN_TILE + t * 2;
    int c0 = 0, c1 = 0;
    if (base < NN)     c0 = rp[base];
    if (base + 1 < NN) c1 = rp[base + 1];
    const int s = c0 + c1;
    __shared__ int tmp[256];
    tmp[t] = s;
    __syncthreads();
    for (int off = 1; off < 256; off <<= 1) {
        const int v = (t >= off) ? tmp[t - off] : 0;
        __syncthreads();
        tmp[t] += v;
        __syncthreads();
    }
    const int excl = tmp[t] - s;
    if (base < NN)     rp[base]     = excl;
    if (base + 1 < NN) rp[base + 1] = excl + c0;
    if (t == 255) part[blockIdx.x] = tmp[255];
}

__global__ __launch_bounds__(256) void scan2_kernel(int* __restrict__ part)
{
    const int t = threadIdx.x;
    const int s = (t < NB1) ? part[t] : 0;
    __shared__ int tmp[256];
    tmp[t] = s;
    __syncthreads();
    for (int off = 1; off < 256; off <<= 1) {
        const int v = (t >= off) ? tmp[t - off] : 0;
        __syncthreads();
        tmp[t] += v;
        __syncthreads();
    }
    if (t < NB1) part[t] = tmp[t] - s;   // exclusive across tiles
}

// ---------------------------------------------------------------------------
// CSR build 3: permute edges into slots (no atomics).
// ---------------------------------------------------------------------------
__global__ __launch_bounds__(256) void permute_kernel(
    const int* __restrict__ src, const int* __restrict__ dst,
    const float* __restrict__ val, const int* __restrict__ rp,
    const int* __restrict__ part, const int* __restrict__ rank,
    int2* __restrict__ csr)
{
    const int e = blockIdx.x * 256 + threadIdx.x;
    const int s = src[e];
    const int pos = rp[s] + part[s >> 9] + rank[e];
    csr[pos] = make_int2(dst[e], __float_as_int(val[e]));
}

// ---------------------------------------------------------------------------
// SpMM v2 (CSR, bf16 feat): one row per 64-lane wave; wave split into 4
// 16-lane groups, each gathering a DIFFERENT edge's 256B row (dwordx4/lane).
// 8 edges in flight per iteration; inactive slots use val=0 (dst=0 is a safe
// dummy gather). Epilogue: shfl_xor(16,32) cross-group reduce, groups share
// the same output row. f32 accumulate, bf16 output.
// ---------------------------------------------------------------------------
__global__ __launch_bounds__(256) void spmm_csr_bf16(
    const int* __restrict__ rp, const int* __restrict__ part,
    const int2* __restrict__ csr, const ushort* __restrict__ featb,
    ushort* __restrict__ outb)
{
    const int tid  = blockIdx.x * 256 + threadIdx.x;
    const int row  = tid >> 6;
    const int lane = threadIdx.x & 63;
    const int g    = lane >> 4;      // edge slot 0..3
    const int li   = lane & 15;      // 16B segment within row

    const int start = rp[row] + part[row >> 9];
    const int end   = (row == NN - 1) ? EE : (rp[row + 1] + part[(row + 1) >> 9]);

    float acc[8] = {0.f, 0.f, 0.f, 0.f, 0.f, 0.f, 0.f, 0.f};

    for (int base = start; base < end; base += 8) {
        const int p0 = base + g;
        const int p1 = base + 4 + g;
        int2 e0 = make_int2(0, 0), e1 = make_int2(0, 0);
        if (p0 < end) e0 = csr[p0];
        if (p1 < end) e1 = csr[p1];
        const float v0 = __int_as_float(e0.y);   // 0.0f when inactive
        const float v1 = __int_as_float(e1.y);
        const uint4 g0 = *reinterpret_cast<const uint4*>(featb + (size_t)e0.x * 128 + li * 8);
        const uint4 g1 = *reinterpret_cast<const uint4*>(featb + (size_t)e1.x * 128 + li * 8);
        acc[0] = fmaf(v0, bflo(g0.x), acc[0]); acc[1] = fmaf(v0, bfhi(g0.x), acc[1]);
        acc[2] = fmaf(v0, bflo(g0.y), acc[2]); acc[3] = fmaf(v0, bfhi(g0.y), acc[3]);
        acc[4] = fmaf(v0, bflo(g0.z), acc[4]); acc[5] = fmaf(v0, bfhi(g0.z), acc[5]);
        acc[6] = fmaf(v0, bflo(g0.w), acc[6]); acc[7] = fmaf(v0, bfhi(g0.w), acc[7]);
        acc[0] = fmaf(v1, bflo(g1.x), acc[0]); acc[1] = fmaf(v1, bfhi(g1.x), acc[1]);
        acc[2] = fmaf(v1, bflo(g1.y), acc[2]); acc[3] = fmaf(v1, bfhi(g1.y), acc[3]);
        acc[4] = fmaf(v1, bflo(g1.z), acc[4]); acc[5] = fmaf(v1, bfhi(g1.z), acc[5]);
        acc[6] = fmaf(v1, bflo(g1.w), acc[6]); acc[7] = fmaf(v1, bfhi(g1.w), acc[7]);
    }

    #pragma unroll
    for (int i = 0; i < 8; ++i) {
        acc[i] += __shfl_xor(acc[i], 16);
        acc[i] += __shfl_xor(acc[i], 32);
    }

    if (g == 0) {
        uint4 o;
        o.x = ((uint)f2bf(acc[1]) << 16) | (uint)f2bf(acc[0]);
        o.y = ((uint)f2bf(acc[3]) << 16) | (uint)f2bf(acc[2]);
        o.z = ((uint)f2bf(acc[5]) << 16) | (uint)f2bf(acc[4]);
        o.w = ((uint)f2bf(acc[7]) << 16) | (uint)f2bf(acc[6]);
        *reinterpret_cast<uint4*>(outb + (size_t)row * 128 + li * 8) = o;
    }
}

// ---------------------------------------------------------------------------
// GEMM v3: out[N,128] = concat(xb,f1b,f2b)[N,384](bf16) @ Wb[128,384]^T + b
// MFMA 16x16x32_bf16. BM=128, 512 threads = 8 waves, wave w owns rows
// w*16..+15. A-fragments load DIRECT from global (lane lr=row, lg*8=k offset,
// 16B contiguous) -- no A staging. Only W staged in LDS (16KB/iter,
// XOR-swizzled chunks). C/D: col=lane&15, row=(lane>>4)*4+reg.
// ---------------------------------------------------------------------------
__global__ __launch_bounds__(512) void gemm_mfma(
    const ushort* __restrict__ xb, const ushort* __restrict__ f1b,
    const ushort* __restrict__ f2b, const ushort* __restrict__ Wb,
    const float* __restrict__ b, float* __restrict__ out)
{
    __shared__ ushort Ws[128 * 64];

    const int t    = threadIdx.x;
    const int wave = t >> 6;
    const int lane = t & 63;
    const int lr   = lane & 15;
    const int lg   = lane >> 4;
    const int rbase = blockIdx.x * 128;

    int arow = rbase + wave * 16 + lr;
    if (arow >= NN) arow = NN - 1;          // clamp; stores are guarded

    f32x4 acc[8];
    #pragma unroll
    for (int j = 0; j < 8; ++j) {
        const float bv = b[j * 16 + lr];
        acc[j] = (f32x4){bv, bv, bv, bv};
    }

    for (int c = 0; c < 6; ++c) {
        const ushort* src = (c < 2) ? xb : ((c < 4) ? f1b : f2b);
        const int col0 = (c & 1) * 64;
        const int k0w  = c * 64;

        // stage W tile: 128 cols x 64 k = 1024 x 16B chunks, 2 per thread
        #pragma unroll
        for (int it = 0; it < 2; ++it) {
            const int idx = it * 512 + t;
            const int col = idx >> 3, seg = idx & 7;
            const s16x8 v = *reinterpret_cast<const s16x8*>(Wb + (size_t)col * 384 + k0w + seg * 8);
            *reinterpret_cast<s16x8*>(&Ws[col * 64 + ((seg ^ (col & 7)) * 8)]) = v;
        }

        // A fragments direct from global (issue before barrier wait)
        const s16x8 a0 = *reinterpret_cast<const s16x8*>(src + (size_t)arow * 128 + col0 + lg * 8);
        const s16x8 a1 = *reinterpret_cast<const s16x8*>(src + (size_t)arow * 128 + col0 + 32 + lg * 8);

        __syncthreads();

        #pragma unroll
        for (int kk = 0; kk < 2; ++kk) {
            const s16x8 a = kk ? a1 : a0;
            #pragma unroll
            for (int j = 0; j < 8; ++j) {
                const int bcol = j * 16 + lr;
                const int bch  = (kk * 4 + lg) ^ (bcol & 7);
                const s16x8 bf = *reinterpret_cast<const s16x8*>(&Ws[bcol * 64 + bch * 8]);
                acc[j] = __builtin_amdgcn_mfma_f32_16x16x32_bf16(a, bf, acc[j], 0, 0, 0);
            }
        }
        __syncthreads();
    }

    #pragma unroll
    for (int j = 0; j < 8; ++j) {
        #pragma unroll
        for (int j2 = 0; j2 < 4; ++j2) {
            const int rg = rbase + wave * 16 + lg * 4 + j2;
            if (rg < NN)
                out[(size_t)rg * 128 + j * 16 + lr] = acc[j][j2];
        }
    }
}

extern "C" void kernel_launch(void* const* d_in, const int* in_sizes, int n_in,
                              void* d_out, int out_size, void* d_ws, size_t ws_size,
                              hipStream_t stream)
{
    const float* x    = (const float*)d_in[0];
    const int*   esrc = (const int*)  d_in[1];
    const int*   edst = (const int*)  d_in[2];
    const float* eval = (const float*)d_in[3];
    const float* W    = (const float*)d_in[4];
    const float* b    = (const float*)d_in[5];
    float* out = (float*)d_out;

    char* ws = (char*)d_ws;
    const size_t FB = (size_t)NN * D * 2;               // 25,600,000 B
    ushort* xb   = (ushort*)(ws);
    ushort* f1b  = (ushort*)(ws + FB);
    ushort* f2b  = (ushort*)(ws + 2 * FB);
    ushort* Wb   = (ushort*)(ws + 3 * FB);              // 98,304 B
    int2*   csr  = (int2*)  (ws + 3 * FB + 98304);      // 12,800,000 B
    int*    rank = (int*)   (ws + 3 * FB + 98304 + (size_t)EE * 8);
    int*    rp   = (int*)   (ws + 3 * FB + 98304 + (size_t)EE * 8 + (size_t)EE * 4);
    int*    part = (int*)   (ws + 3 * FB + 98304 + (size_t)EE * 8 + (size_t)EE * 4 + 400016);

    hipMemsetAsync(rp, 0, (NN + 1) * sizeof(int), stream);

    cvt_bf16<<<(NN * D / 4 + 255) / 256, 256, 0, stream>>>(x, xb, NN * D / 4);
    cvt_bf16<<<(128 * 384 / 4 + 255) / 256, 256, 0, stream>>>(W, Wb, 128 * 384 / 4);

    hist_kernel <<<EE / 256, 256, 0, stream>>>(esrc, rp, rank);
    scan1_kernel<<<NB1, 256, 0, stream>>>(rp, part);
    scan2_kernel<<<1, 256, 0, stream>>>(part);
    permute_kernel<<<EE / 256, 256, 0, stream>>>(esrc, edst, eval, rp, part, rank, csr);

    spmm_csr_bf16<<<NN / 4, 256, 0, stream>>>(rp, part, csr, xb,  f1b);
    spmm_csr_bf16<<<NN / 4, 256, 0, stream>>>(rp, part, csr, f1b, f2b);

    gemm_mfma<<<(NN + 127) / 128, 512, 0, stream>>>(xb, f1b, f2b, Wb, b, out);
}

// Round 9
// 323.294 us; speedup vs baseline: 8.8379x; 1.2006x over previous
//
#include <hip/hip_runtime.h>
#include <hip/hip_bf16.h>

#define NN 100000
#define EE 1600000
#define D 128
#define BKT 391      // buckets = ceil(NN/256), bucket = src >> 8
#define CAP 5120     // slots per bucket; avg fill 4096 (Poisson, +16 sigma margin)

typedef __attribute__((ext_vector_type(4))) float f32x4;
typedef __attribute__((ext_vector_type(8))) short s16x8;   // 8 bf16 in 4 VGPRs

__device__ inline ushort f2bf(float f) {       // f32 -> bf16 RNE
    uint b = __float_as_uint(f);
    return (ushort)((b + 0x7fffu + ((b >> 16) & 1u)) >> 16);
}
__device__ inline float bflo(uint g) { return __uint_as_float(g << 16); }
__device__ inline float bfhi(uint g) { return __uint_as_float(g & 0xffff0000u); }

// ---------------------------------------------------------------------------
// f32 -> bf16 convert, 4 elems/thread. n4 = n/4.
// ---------------------------------------------------------------------------
__global__ __launch_bounds__(256) void cvt_bf16(
    const float* __restrict__ in, ushort* __restrict__ out, int n4)
{
    const int i = blockIdx.x * 256 + threadIdx.x;
    if (i >= n4) return;
    const float4 v = reinterpret_cast<const float4*>(in)[i];
    ushort4 o;
    o.x = f2bf(v.x); o.y = f2bf(v.y); o.z = f2bf(v.z); o.w = f2bf(v.w);
    reinterpret_cast<ushort4*>(out)[i] = o;
}

// ---------------------------------------------------------------------------
// CSR build pass 1: bucket scatter. Each block takes 2048 edges, counts them
// into an LDS histogram over the 391 buckets, reserves per-bucket chunks with
// ONE global returning atomic per (block,bucket), then scatters packed
// {val, dst | srcLocal<<17} into the bucket arrays. Per-edge atomics are LDS.
// cursor[] pre-zeroed; after the pass cursor[b] == bucket size.
// ---------------------------------------------------------------------------
__global__ __launch_bounds__(256) void bucket_pass1(
    const int* __restrict__ src, const int* __restrict__ dst,
    const float* __restrict__ val, int* __restrict__ cursor,
    int2* __restrict__ barr)
{
    __shared__ int cnt[BKT];
    __shared__ int basel[BKT];
    const int t = threadIdx.x;
    for (int u = t; u < BKT; u += 256) cnt[u] = 0;
    __syncthreads();

    int eb[8], elr[8], ew1[8], ev[8];
    const int e0 = blockIdx.x * 2048 + t;
    #pragma unroll
    for (int it = 0; it < 8; ++it) {
        const int e = e0 + it * 256;
        eb[it] = -1;
        if (e < EE) {
            const int s = src[e];
            const int bk = s >> 8;
            eb[it]  = bk;
            elr[it] = atomicAdd(&cnt[bk], 1);          // LDS
            ew1[it] = dst[e] | ((s & 255) << 17);
            ev[it]  = __float_as_int(val[e]);
        }
    }
    __syncthreads();
    for (int u = t; u < BKT; u += 256)
        basel[u] = (cnt[u] > 0) ? atomicAdd(&cursor[u], cnt[u]) : 0;  // global
    __syncthreads();
    #pragma unroll
    for (int it = 0; it < 8; ++it) {
        if (eb[it] >= 0)
            barr[(size_t)eb[it] * CAP + basel[eb[it]] + elr[it]] =
                make_int2(ev[it], ew1[it]);
    }
}

// ---------------------------------------------------------------------------
// CSR build pass 1.5: exclusive scan of the 391 bucket sizes -> bbase[392].
// Also plants rp[NN] = EE.
// ---------------------------------------------------------------------------
__global__ __launch_bounds__(512) void scan_buckets(
    const int* __restrict__ cursor, int* __restrict__ bbase, int* __restrict__ rp)
{
    __shared__ int tmp[512];
    const int t = threadIdx.x;
    const int s = (t < BKT) ? cursor[t] : 0;
    tmp[t] = s;
    __syncthreads();
    for (int off = 1; off < 512; off <<= 1) {
        const int v = (t >= off) ? tmp[t - off] : 0;
        __syncthreads();
        tmp[t] += v;
        __syncthreads();
    }
    if (t < BKT) bbase[t] = tmp[t] - s;
    if (t == BKT - 1) bbase[BKT] = tmp[t];
    if (t == 0) rp[NN] = EE;
}

// ---------------------------------------------------------------------------
// CSR build pass 2: one block per bucket (256 rows). LDS row-histogram with
// returning LDS atomics (per-edge rank), LDS scan -> absolute rp[] for the
// bucket's rows, then scatter edges into final CSR slots.
// ---------------------------------------------------------------------------
__global__ __launch_bounds__(256) void bucket_pass2(
    const int* __restrict__ bbase, const int2* __restrict__ barr,
    int* __restrict__ rp, int2* __restrict__ csr)
{
    __shared__ int rowcnt[256];
    __shared__ int tmp[256];
    __shared__ int rowoff[256];
    __shared__ ushort lrk[CAP];
    const int b = blockIdx.x;
    const int t = threadIdx.x;
    const int gbase = bbase[b];
    const int sz    = bbase[b + 1] - gbase;
    const int2* my  = barr + (size_t)b * CAP;

    rowcnt[t] = 0;
    __syncthreads();
    for (int i = t; i < sz; i += 256) {
        const int rl = (my[i].y >> 17) & 255;
        lrk[i] = (ushort)atomicAdd(&rowcnt[rl], 1);    // LDS
    }
    __syncthreads();
    const int c = rowcnt[t];
    tmp[t] = c;
    __syncthreads();
    for (int off = 1; off < 256; off <<= 1) {
        const int v = (t >= off) ? tmp[t - off] : 0;
        __syncthreads();
        tmp[t] += v;
        __syncthreads();
    }
    rowoff[t] = tmp[t] - c;                            // exclusive within bucket
    const int row = b * 256 + t;
    if (row < NN) rp[row] = gbase + (tmp[t] - c);
    __syncthreads();
    for (int i = t; i < sz; i += 256) {
        const int2 e = my[i];
        const int rl = (e.y >> 17) & 255;
        csr[gbase + rowoff[rl] + lrk[i]] = make_int2(e.y & 0x1FFFF, e.x);
    }
}

// ---------------------------------------------------------------------------
// SpMM v2 (CSR, bf16 feat): one row per 64-lane wave; wave split into 4
// 16-lane groups, each gathering a DIFFERENT edge's 256B row (dwordx4/lane).
// 8 edges in flight per iteration; inactive slots use val=0. Epilogue:
// shfl_xor(16,32) cross-group reduce. f32 accumulate, bf16 output.
// ---------------------------------------------------------------------------
__global__ __launch_bounds__(256) void spmm_csr_bf16(
    const int* __restrict__ rp, const int2* __restrict__ csr,
    const ushort* __restrict__ featb, ushort* __restrict__ outb)
{
    const int tid  = blockIdx.x * 256 + threadIdx.x;
    const int row  = tid >> 6;
    const int lane = threadIdx.x & 63;
    const int g    = lane >> 4;      // edge slot 0..3
    const int li   = lane & 15;      // 16B segment within row

    const int start = rp[row];
    const int end   = rp[row + 1];

    float acc[8] = {0.f, 0.f, 0.f, 0.f, 0.f, 0.f, 0.f, 0.f};

    for (int base = start; base < end; base += 8) {
        const int p0 = base + g;
        const int p1 = base + 4 + g;
        int2 e0 = make_int2(0, 0), e1 = make_int2(0, 0);
        if (p0 < end) e0 = csr[p0];
        if (p1 < end) e1 = csr[p1];
        const float v0 = __int_as_float(e0.y);   // 0.0f when inactive
        const float v1 = __int_as_float(e1.y);
        const uint4 g0 = *reinterpret_cast<const uint4*>(featb + (size_t)e0.x * 128 + li * 8);
        const uint4 g1 = *reinterpret_cast<const uint4*>(featb + (size_t)e1.x * 128 + li * 8);
        acc[0] = fmaf(v0, bflo(g0.x), acc[0]); acc[1] = fmaf(v0, bfhi(g0.x), acc[1]);
        acc[2] = fmaf(v0, bflo(g0.y), acc[2]); acc[3] = fmaf(v0, bfhi(g0.y), acc[3]);
        acc[4] = fmaf(v0, bflo(g0.z), acc[4]); acc[5] = fmaf(v0, bfhi(g0.z), acc[5]);
        acc[6] = fmaf(v0, bflo(g0.w), acc[6]); acc[7] = fmaf(v0, bfhi(g0.w), acc[7]);
        acc[0] = fmaf(v1, bflo(g1.x), acc[0]); acc[1] = fmaf(v1, bfhi(g1.x), acc[1]);
        acc[2] = fmaf(v1, bflo(g1.y), acc[2]); acc[3] = fmaf(v1, bfhi(g1.y), acc[3]);
        acc[4] = fmaf(v1, bflo(g1.z), acc[4]); acc[5] = fmaf(v1, bfhi(g1.z), acc[5]);
        acc[6] = fmaf(v1, bflo(g1.w), acc[6]); acc[7] = fmaf(v1, bfhi(g1.w), acc[7]);
    }

    #pragma unroll
    for (int i = 0; i < 8; ++i) {
        acc[i] += __shfl_xor(acc[i], 16);
        acc[i] += __shfl_xor(acc[i], 32);
    }

    if (g == 0) {
        uint4 o;
        o.x = ((uint)f2bf(acc[1]) << 16) | (uint)f2bf(acc[0]);
        o.y = ((uint)f2bf(acc[3]) << 16) | (uint)f2bf(acc[2]);
        o.z = ((uint)f2bf(acc[5]) << 16) | (uint)f2bf(acc[4]);
        o.w = ((uint)f2bf(acc[7]) << 16) | (uint)f2bf(acc[6]);
        *reinterpret_cast<uint4*>(outb + (size_t)row * 128 + li * 8) = o;
    }
}

// ---------------------------------------------------------------------------
// GEMM v3: out[N,128] = concat(xb,f1b,f2b)[N,384](bf16) @ Wb[128,384]^T + b
// MFMA 16x16x32_bf16. BM=128, 512 threads = 8 waves. A direct from global;
// only W staged in LDS (XOR-swizzled). C/D: col=lane&15, row=(lane>>4)*4+reg.
// ---------------------------------------------------------------------------
__global__ __launch_bounds__(512) void gemm_mfma(
    const ushort* __restrict__ xb, const ushort* __restrict__ f1b,
    const ushort* __restrict__ f2b, const ushort* __restrict__ Wb,
    const float* __restrict__ b, float* __restrict__ out)
{
    __shared__ ushort Ws[128 * 64];

    const int t    = threadIdx.x;
    const int wave = t >> 6;
    const int lane = t & 63;
    const int lr   = lane & 15;
    const int lg   = lane >> 4;
    const int rbase = blockIdx.x * 128;

    int arow = rbase + wave * 16 + lr;
    if (arow >= NN) arow = NN - 1;          // clamp; stores are guarded

    f32x4 acc[8];
    #pragma unroll
    for (int j = 0; j < 8; ++j) {
        const float bv = b[j * 16 + lr];
        acc[j] = (f32x4){bv, bv, bv, bv};
    }

    for (int c = 0; c < 6; ++c) {
        const ushort* src = (c < 2) ? xb : ((c < 4) ? f1b : f2b);
        const int col0 = (c & 1) * 64;
        const int k0w  = c * 64;

        #pragma unroll
        for (int it = 0; it < 2; ++it) {
            const int idx = it * 512 + t;
            const int col = idx >> 3, seg = idx & 7;
            const s16x8 v = *reinterpret_cast<const s16x8*>(Wb + (size_t)col * 384 + k0w + seg * 8);
            *reinterpret_cast<s16x8*>(&Ws[col * 64 + ((seg ^ (col & 7)) * 8)]) = v;
        }

        const s16x8 a0 = *reinterpret_cast<const s16x8*>(src + (size_t)arow * 128 + col0 + lg * 8);
        const s16x8 a1 = *reinterpret_cast<const s16x8*>(src + (size_t)arow * 128 + col0 + 32 + lg * 8);

        __syncthreads();

        #pragma unroll
        for (int kk = 0; kk < 2; ++kk) {
            const s16x8 a = kk ? a1 : a0;
            #pragma unroll
            for (int j = 0; j < 8; ++j) {
                const int bcol = j * 16 + lr;
                const int bch  = (kk * 4 + lg) ^ (bcol & 7);
                const s16x8 bf = *reinterpret_cast<const s16x8*>(&Ws[bcol * 64 + bch * 8]);
                acc[j] = __builtin_amdgcn_mfma_f32_16x16x32_bf16(a, bf, acc[j], 0, 0, 0);
            }
        }
        __syncthreads();
    }

    #pragma unroll
    for (int j = 0; j < 8; ++j) {
        #pragma unroll
        for (int j2 = 0; j2 < 4; ++j2) {
            const int rg = rbase + wave * 16 + lg * 4 + j2;
            if (rg < NN)
                out[(size_t)rg * 128 + j * 16 + lr] = acc[j][j2];
        }
    }
}

extern "C" void kernel_launch(void* const* d_in, const int* in_sizes, int n_in,
                              void* d_out, int out_size, void* d_ws, size_t ws_size,
                              hipStream_t stream)
{
    const float* x    = (const float*)d_in[0];
    const int*   esrc = (const int*)  d_in[1];
    const int*   edst = (const int*)  d_in[2];
    const float* eval = (const float*)d_in[3];
    const float* W    = (const float*)d_in[4];
    const float* b    = (const float*)d_in[5];
    float* out = (float*)d_out;

    char* ws = (char*)d_ws;
    const size_t FB = (size_t)NN * D * 2;                 // 25,600,000 B
    ushort* xb     = (ushort*)(ws);
    ushort* f1b    = (ushort*)(ws + FB);
    ushort* f2b    = (ushort*)(ws + 2 * FB);
    ushort* Wb     = (ushort*)(ws + 3 * FB);              // 98,304 B
    char*   p      = ws + 3 * FB + 98304;
    int2*   csr    = (int2*)p;               p += (size_t)EE * 8;        // 12.8 MB
    int2*   barr   = (int2*)p;               p += (size_t)BKT * CAP * 8; // 16.0 MB
    int*    cursor = (int*)p;                p += (BKT + 1) * 4;
    int*    bbase  = (int*)p;                p += (BKT + 1) * 4;
    int*    rp     = (int*)p;                                            // (NN+1)*4

    hipMemsetAsync(cursor, 0, BKT * sizeof(int), stream);

    cvt_bf16<<<(NN * D / 4 + 255) / 256, 256, 0, stream>>>(x, xb, NN * D / 4);
    cvt_bf16<<<(128 * 384 / 4 + 255) / 256, 256, 0, stream>>>(W, Wb, 128 * 384 / 4);

    bucket_pass1<<<(EE + 2047) / 2048, 256, 0, stream>>>(esrc, edst, eval, cursor, barr);
    scan_buckets<<<1, 512, 0, stream>>>(cursor, bbase, rp);
    bucket_pass2<<<BKT, 256, 0, stream>>>(bbase, barr, rp, csr);

    spmm_csr_bf16<<<NN / 4, 256, 0, stream>>>(rp, csr, xb,  f1b);
    spmm_csr_bf16<<<NN / 4, 256, 0, stream>>>(rp, csr, f1b, f2b);

    gemm_mfma<<<(NN + 127) / 128, 512, 0, stream>>>(xb, f1b, f2b, Wb, b, out);
}

// Round 10
// 315.785 us; speedup vs baseline: 9.0480x; 1.0238x over previous
//
#include <hip/hip_runtime.h>
#include <hip/hip_bf16.h>

#define NN 100000
#define EE 1600000
#define D 128
#define BKT 391      // buckets = ceil(NN/256), bucket = src >> 8
#define CAP 5120     // slots per bucket; avg fill 4096 (Poisson, +16 sigma margin)

typedef __attribute__((ext_vector_type(4))) float f32x4;
typedef __attribute__((ext_vector_type(8))) short s16x8;   // 8 bf16 in 4 VGPRs

__device__ inline ushort f2bf(float f) {       // f32 -> bf16 RNE
    uint b = __float_as_uint(f);
    return (ushort)((b + 0x7fffu + ((b >> 16) & 1u)) >> 16);
}
__device__ inline float bflo(uint g) { return __uint_as_float(g << 16); }
__device__ inline float bfhi(uint g) { return __uint_as_float(g & 0xffff0000u); }

// ---------------------------------------------------------------------------
// f32 -> bf16 convert, 4 elems/thread. n4 = n/4.
// ---------------------------------------------------------------------------
__global__ __launch_bounds__(256) void cvt_bf16(
    const float* __restrict__ in, ushort* __restrict__ out, int n4)
{
    const int i = blockIdx.x * 256 + threadIdx.x;
    if (i >= n4) return;
    const float4 v = reinterpret_cast<const float4*>(in)[i];
    ushort4 o;
    o.x = f2bf(v.x); o.y = f2bf(v.y); o.z = f2bf(v.z); o.w = f2bf(v.w);
    reinterpret_cast<ushort4*>(out)[i] = o;
}

// ---------------------------------------------------------------------------
// CSR build pass 1 (LDS-presorted bucket scatter). Per block of 2048 edges:
//   A) LDS histogram over 391 buckets + per-edge LDS rank
//   B) LDS scan of cnt -> lbase; ONE global returning atomic per bucket -> gbase
//   C) scatter edges into LDS staged[] sorted by bucket
//   D) write staged[] out; consecutive i -> consecutive slots within a bucket
//      run, so global writes are coalesced (was 7x line amplification).
// cursor[] pre-zeroed; afterwards cursor[b] == bucket size.
// ---------------------------------------------------------------------------
__global__ __launch_bounds__(256) void bucket_pass1(
    const int* __restrict__ src, const int* __restrict__ dst,
    const float* __restrict__ val, int* __restrict__ cursor,
    int2* __restrict__ barr)
{
    __shared__ int    cnt[BKT];
    __shared__ int    lbase[BKT];
    __shared__ int    gbase[BKT];
    __shared__ int    tmp[256];
    __shared__ int2   staged[2048];
    __shared__ ushort bkt_of[2048];
    const int t = threadIdx.x;
    for (int u = t; u < BKT; u += 256) cnt[u] = 0;
    __syncthreads();

    int ebk[8], erk[8]; int2 epk[8];
    const int e0 = blockIdx.x * 2048 + t;
    #pragma unroll
    for (int it = 0; it < 8; ++it) {
        const int e = e0 + it * 256;
        ebk[it] = -1;
        if (e < EE) {
            const int s = src[e];
            const int bk = s >> 8;
            ebk[it] = bk;
            erk[it] = atomicAdd(&cnt[bk], 1);          // LDS
            epk[it] = make_int2(__float_as_int(val[e]), dst[e] | ((s & 255) << 17));
        }
    }
    __syncthreads();

    // scan cnt[0..390] -> lbase (exclusive), 2 elems/thread
    {
        const int i0 = 2 * t, i1 = 2 * t + 1;
        const int c0 = (i0 < BKT) ? cnt[i0] : 0;
        const int c1 = (i1 < BKT) ? cnt[i1] : 0;
        const int s = c0 + c1;
        tmp[t] = s;
        __syncthreads();
        for (int off = 1; off < 256; off <<= 1) {
            const int v = (t >= off) ? tmp[t - off] : 0;
            __syncthreads();
            tmp[t] += v;
            __syncthreads();
        }
        const int excl = tmp[t] - s;
        if (i0 < BKT) lbase[i0] = excl;
        if (i1 < BKT) lbase[i1] = excl + c0;
    }
    for (int u = t; u < BKT; u += 256)
        gbase[u] = (cnt[u] > 0) ? atomicAdd(&cursor[u], cnt[u]) : 0;   // global
    __syncthreads();

    #pragma unroll
    for (int it = 0; it < 8; ++it) {
        if (ebk[it] >= 0) {
            const int pos = lbase[ebk[it]] + erk[it];
            staged[pos] = epk[it];
            bkt_of[pos] = (ushort)ebk[it];
        }
    }
    __syncthreads();

    const int total = min(2048, EE - blockIdx.x * 2048);
    for (int i = t; i < total; i += 256) {
        const int bk = bkt_of[i];
        barr[(size_t)bk * CAP + gbase[bk] + (i - lbase[bk])] = staged[i];
    }
}

// ---------------------------------------------------------------------------
// CSR build pass 1.5: exclusive scan of the 391 bucket sizes -> bbase[392].
// Also plants rp[NN] = EE.
// ---------------------------------------------------------------------------
__global__ __launch_bounds__(512) void scan_buckets(
    const int* __restrict__ cursor, int* __restrict__ bbase, int* __restrict__ rp)
{
    __shared__ int tmp[512];
    const int t = threadIdx.x;
    const int s = (t < BKT) ? cursor[t] : 0;
    tmp[t] = s;
    __syncthreads();
    for (int off = 1; off < 512; off <<= 1) {
        const int v = (t >= off) ? tmp[t - off] : 0;
        __syncthreads();
        tmp[t] += v;
        __syncthreads();
    }
    if (t < BKT) bbase[t] = tmp[t] - s;
    if (t == BKT - 1) bbase[BKT] = tmp[t];
    if (t == 0) rp[NN] = EE;
}

// ---------------------------------------------------------------------------
// CSR build pass 2: one block per bucket (256 rows). Count rows, LDS scan ->
// rp[]; reorder edges into LDS sorted[] via returning LDS atomics; write csr
// perfectly sequentially (coalesced).
// ---------------------------------------------------------------------------
__global__ __launch_bounds__(256) void bucket_pass2(
    const int* __restrict__ bbase, const int2* __restrict__ barr,
    int* __restrict__ rp, int2* __restrict__ csr)
{
    __shared__ int rowcnt[256];
    __shared__ int tmp[256];
    __shared__ int rowcur[256];
    __shared__ int2 sorted[CAP];       // 40 KB
    const int b = blockIdx.x;
    const int t = threadIdx.x;
    const int gb = bbase[b];
    const int sz = bbase[b + 1] - gb;
    const int2* my = barr + (size_t)b * CAP;

    rowcnt[t] = 0;
    __syncthreads();
    for (int i = t; i < sz; i += 256)
        atomicAdd(&rowcnt[(my[i].y >> 17) & 255], 1);  // LDS
    __syncthreads();
    const int c = rowcnt[t];
    tmp[t] = c;
    __syncthreads();
    for (int off = 1; off < 256; off <<= 1) {
        const int v = (t >= off) ? tmp[t - off] : 0;
        __syncthreads();
        tmp[t] += v;
        __syncthreads();
    }
    const int excl = tmp[t] - c;
    rowcur[t] = excl;
    const int row = b * 256 + t;
    if (row < NN) rp[row] = gb + excl;
    __syncthreads();
    for (int i = t; i < sz; i += 256) {
        const int2 e = my[i];
        const int rl = (e.y >> 17) & 255;
        const int slot = atomicAdd(&rowcur[rl], 1);    // LDS, returning
        sorted[slot] = make_int2(e.y & 0x1FFFF, e.x);
    }
    __syncthreads();
    for (int i = t; i < sz; i += 256)
        csr[gb + i] = sorted[i];
}

// ---------------------------------------------------------------------------
// SpMM v3 (CSR, bf16 feat): one row per 64-lane wave; 4x 16-lane groups each
// gather a DIFFERENT edge's 256B row (dwordx4/lane). 16 edges per iteration,
// 4 gathers + 4 csr loads in flight per lane. Out-of-range slots clamp to
// `start` with v=0 (duplicate gather is L1/L2-hot). Epilogue: shfl_xor(16,32)
// cross-group reduce. f32 accumulate, bf16 output.
// ---------------------------------------------------------------------------
__global__ __launch_bounds__(256) void spmm_csr_bf16(
    const int* __restrict__ rp, const int2* __restrict__ csr,
    const ushort* __restrict__ featb, ushort* __restrict__ outb)
{
    const int tid  = blockIdx.x * 256 + threadIdx.x;
    const int row  = tid >> 6;
    const int lane = threadIdx.x & 63;
    const int g    = lane >> 4;      // edge slot 0..3
    const int li   = lane & 15;      // 16B segment within row

    const int start = rp[row];
    const int end   = rp[row + 1];

    float acc[8] = {0.f, 0.f, 0.f, 0.f, 0.f, 0.f, 0.f, 0.f};

    for (int base = start; base < end; base += 16) {
        #pragma unroll
        for (int k = 0; k < 4; ++k) {
            const int p  = base + k * 4 + g;
            const int pc = (p < end) ? p : start;       // safe duplicate slot
            const int2 e = csr[pc];
            const float v = (p < end) ? __int_as_float(e.y) : 0.f;
            const uint4 gg = *reinterpret_cast<const uint4*>(featb + (size_t)e.x * 128 + li * 8);
            acc[0] = fmaf(v, bflo(gg.x), acc[0]); acc[1] = fmaf(v, bfhi(gg.x), acc[1]);
            acc[2] = fmaf(v, bflo(gg.y), acc[2]); acc[3] = fmaf(v, bfhi(gg.y), acc[3]);
            acc[4] = fmaf(v, bflo(gg.z), acc[4]); acc[5] = fmaf(v, bfhi(gg.z), acc[5]);
            acc[6] = fmaf(v, bflo(gg.w), acc[6]); acc[7] = fmaf(v, bfhi(gg.w), acc[7]);
        }
    }

    #pragma unroll
    for (int i = 0; i < 8; ++i) {
        acc[i] += __shfl_xor(acc[i], 16);
        acc[i] += __shfl_xor(acc[i], 32);
    }

    if (g == 0) {
        uint4 o;
        o.x = ((uint)f2bf(acc[1]) << 16) | (uint)f2bf(acc[0]);
        o.y = ((uint)f2bf(acc[3]) << 16) | (uint)f2bf(acc[2]);
        o.z = ((uint)f2bf(acc[5]) << 16) | (uint)f2bf(acc[4]);
        o.w = ((uint)f2bf(acc[7]) << 16) | (uint)f2bf(acc[6]);
        *reinterpret_cast<uint4*>(outb + (size_t)row * 128 + li * 8) = o;
    }
}

// ---------------------------------------------------------------------------
// GEMM v3: out[N,128] = concat(xb,f1b,f2b)[N,384](bf16) @ Wb[128,384]^T + b
// MFMA 16x16x32_bf16. BM=128, 512 threads = 8 waves. A direct from global;
// only W staged in LDS (XOR-swizzled). C/D: col=lane&15, row=(lane>>4)*4+reg.
// ---------------------------------------------------------------------------
__global__ __launch_bounds__(512) void gemm_mfma(
    const ushort* __restrict__ xb, const ushort* __restrict__ f1b,
    const ushort* __restrict__ f2b, const ushort* __restrict__ Wb,
    const float* __restrict__ b, float* __restrict__ out)
{
    __shared__ ushort Ws[128 * 64];

    const int t    = threadIdx.x;
    const int wave = t >> 6;
    const int lane = t & 63;
    const int lr   = lane & 15;
    const int lg   = lane >> 4;
    const int rbase = blockIdx.x * 128;

    int arow = rbase + wave * 16 + lr;
    if (arow >= NN) arow = NN - 1;          // clamp; stores are guarded

    f32x4 acc[8];
    #pragma unroll
    for (int j = 0; j < 8; ++j) {
        const float bv = b[j * 16 + lr];
        acc[j] = (f32x4){bv, bv, bv, bv};
    }

    for (int c = 0; c < 6; ++c) {
        const ushort* src = (c < 2) ? xb : ((c < 4) ? f1b : f2b);
        const int col0 = (c & 1) * 64;
        const int k0w  = c * 64;

        #pragma unroll
        for (int it = 0; it < 2; ++it) {
            const int idx = it * 512 + t;
            const int col = idx >> 3, seg = idx & 7;
            const s16x8 v = *reinterpret_cast<const s16x8*>(Wb + (size_t)col * 384 + k0w + seg * 8);
            *reinterpret_cast<s16x8*>(&Ws[col * 64 + ((seg ^ (col & 7)) * 8)]) = v;
        }

        const s16x8 a0 = *reinterpret_cast<const s16x8*>(src + (size_t)arow * 128 + col0 + lg * 8);
        const s16x8 a1 = *reinterpret_cast<const s16x8*>(src + (size_t)arow * 128 + col0 + 32 + lg * 8);

        __syncthreads();

        #pragma unroll
        for (int kk = 0; kk < 2; ++kk) {
            const s16x8 a = kk ? a1 : a0;
            #pragma unroll
            for (int j = 0; j < 8; ++j) {
                const int bcol = j * 16 + lr;
                const int bch  = (kk * 4 + lg) ^ (bcol & 7);
                const s16x8 bf = *reinterpret_cast<const s16x8*>(&Ws[bcol * 64 + bch * 8]);
                acc[j] = __builtin_amdgcn_mfma_f32_16x16x32_bf16(a, bf, acc[j], 0, 0, 0);
            }
        }
        __syncthreads();
    }

    #pragma unroll
    for (int j = 0; j < 8; ++j) {
        #pragma unroll
        for (int j2 = 0; j2 < 4; ++j2) {
            const int rg = rbase + wave * 16 + lg * 4 + j2;
            if (rg < NN)
                out[(size_t)rg * 128 + j * 16 + lr] = acc[j][j2];
        }
    }
}

extern "C" void kernel_launch(void* const* d_in, const int* in_sizes, int n_in,
                              void* d_out, int out_size, void* d_ws, size_t ws_size,
                              hipStream_t stream)
{
    const float* x    = (const float*)d_in[0];
    const int*   esrc = (const int*)  d_in[1];
    const int*   edst = (const int*)  d_in[2];
    const float* eval = (const float*)d_in[3];
    const float* W    = (const float*)d_in[4];
    const float* b    = (const float*)d_in[5];
    float* out = (float*)d_out;

    char* ws = (char*)d_ws;
    const size_t FB = (size_t)NN * D * 2;                 // 25,600,000 B
    ushort* xb     = (ushort*)(ws);
    ushort* f1b    = (ushort*)(ws + FB);
    ushort* f2b    = (ushort*)(ws + 2 * FB);
    ushort* Wb     = (ushort*)(ws + 3 * FB);              // 98,304 B
    char*   p      = ws + 3 * FB + 98304;
    int2*   csr    = (int2*)p;               p += (size_t)EE * 8;        // 12.8 MB
    int2*   barr   = (int2*)p;               p += (size_t)BKT * CAP * 8; // 16.0 MB
    int*    cursor = (int*)p;                p += (BKT + 1) * 4;
    int*    bbase  = (int*)p;                p += (BKT + 1) * 4;
    int*    rp     = (int*)p;                                            // (NN+1)*4

    hipMemsetAsync(cursor, 0, BKT * sizeof(int), stream);

    cvt_bf16<<<(NN * D / 4 + 255) / 256, 256, 0, stream>>>(x, xb, NN * D / 4);
    cvt_bf16<<<(128 * 384 / 4 + 255) / 256, 256, 0, stream>>>(W, Wb, 128 * 384 / 4);

    bucket_pass1<<<(EE + 2047) / 2048, 256, 0, stream>>>(esrc, edst, eval, cursor, barr);
    scan_buckets<<<1, 512, 0, stream>>>(cursor, bbase, rp);
    bucket_pass2<<<BKT, 256, 0, stream>>>(bbase, barr, rp, csr);

    spmm_csr_bf16<<<NN / 4, 256, 0, stream>>>(rp, csr, xb,  f1b);
    spmm_csr_bf16<<<NN / 4, 256, 0, stream>>>(rp, csr, f1b, f2b);

    gemm_mfma<<<(NN + 127) / 128, 512, 0, stream>>>(xb, f1b, f2b, Wb, b, out);
}

// Round 11
// 311.716 us; speedup vs baseline: 9.1661x; 1.0131x over previous
//
#include <hip/hip_runtime.h>
#include <hip/hip_bf16.h>

#define NN 100000
#define EE 1600000
#define D 128
#define BKT 391      // buckets = ceil(NN/256), bucket = src >> 8
#define CAP 5120     // slots per bucket; avg fill 4096 (+16 sigma margin)
#define P1E 4096     // edges per pass1 block

typedef __attribute__((ext_vector_type(4))) float f32x4;
typedef __attribute__((ext_vector_type(8))) short s16x8;   // 8 bf16 in 4 VGPRs

__device__ inline ushort f2bf(float f) {       // f32 -> bf16 RNE
    uint b = __float_as_uint(f);
    return (ushort)((b + 0x7fffu + ((b >> 16) & 1u)) >> 16);
}
__device__ inline float bflo(uint g) { return __uint_as_float(g << 16); }
__device__ inline float bfhi(uint g) { return __uint_as_float(g & 0xffff0000u); }

// ---------------------------------------------------------------------------
// f32 -> bf16 convert for BOTH x and W in one launch.
// ---------------------------------------------------------------------------
#define XN4 (NN * D / 4)
#define WN4 (128 * 384 / 4)
__global__ __launch_bounds__(256) void cvt_both(
    const float* __restrict__ x, ushort* __restrict__ xb,
    const float* __restrict__ W, ushort* __restrict__ Wb)
{
    const int i = blockIdx.x * 256 + threadIdx.x;
    if (i < XN4) {
        const float4 v = reinterpret_cast<const float4*>(x)[i];
        ushort4 o;
        o.x = f2bf(v.x); o.y = f2bf(v.y); o.z = f2bf(v.z); o.w = f2bf(v.w);
        reinterpret_cast<ushort4*>(xb)[i] = o;
    } else if (i < XN4 + WN4) {
        const int j = i - XN4;
        const float4 v = reinterpret_cast<const float4*>(W)[j];
        ushort4 o;
        o.x = f2bf(v.x); o.y = f2bf(v.y); o.z = f2bf(v.z); o.w = f2bf(v.w);
        reinterpret_cast<ushort4*>(Wb)[j] = o;
    }
}

// ---------------------------------------------------------------------------
// CSR build pass 1 (LDS-presorted bucket scatter), 4096 edges/block:
//   A) LDS histogram over 391 buckets + per-edge LDS rank
//   B) LDS scan -> lbase; ONE global returning atomic per (block,bucket)
//   C) scatter edges into LDS staged[] sorted by bucket
//   D) write staged[] out coalesced (bucket runs are contiguous).
// cursor[] pre-zeroed; afterwards cursor[b] == bucket size.
// ---------------------------------------------------------------------------
__global__ __launch_bounds__(256) void bucket_pass1(
    const int* __restrict__ src, const int* __restrict__ dst,
    const float* __restrict__ val, int* __restrict__ cursor,
    int2* __restrict__ barr)
{
    __shared__ int    cnt[BKT];
    __shared__ int    lbase[BKT];
    __shared__ int    gbase[BKT];
    __shared__ int    tmp[256];
    __shared__ int2   staged[P1E];     // 32 KB
    __shared__ ushort bkt_of[P1E];     // 8 KB
    const int t = threadIdx.x;
    for (int u = t; u < BKT; u += 256) cnt[u] = 0;
    __syncthreads();

    int ebk[16], erk[16]; int2 epk[16];
    const int e0 = blockIdx.x * P1E + t;
    #pragma unroll
    for (int it = 0; it < 16; ++it) {
        const int e = e0 + it * 256;
        ebk[it] = -1;
        if (e < EE) {
            const int s = src[e];
            const int bk = s >> 8;
            ebk[it] = bk;
            erk[it] = atomicAdd(&cnt[bk], 1);          // LDS
            epk[it] = make_int2(__float_as_int(val[e]), dst[e] | ((s & 255) << 17));
        }
    }
    __syncthreads();

    // scan cnt[0..390] -> lbase (exclusive), 2 elems/thread
    {
        const int i0 = 2 * t, i1 = 2 * t + 1;
        const int c0 = (i0 < BKT) ? cnt[i0] : 0;
        const int c1 = (i1 < BKT) ? cnt[i1] : 0;
        const int s = c0 + c1;
        tmp[t] = s;
        __syncthreads();
        for (int off = 1; off < 256; off <<= 1) {
            const int v = (t >= off) ? tmp[t - off] : 0;
            __syncthreads();
            tmp[t] += v;
            __syncthreads();
        }
        const int excl = tmp[t] - s;
        if (i0 < BKT) lbase[i0] = excl;
        if (i1 < BKT) lbase[i1] = excl + c0;
    }
    for (int u = t; u < BKT; u += 256)
        gbase[u] = (cnt[u] > 0) ? atomicAdd(&cursor[u], cnt[u]) : 0;   // global
    __syncthreads();

    #pragma unroll
    for (int it = 0; it < 16; ++it) {
        if (ebk[it] >= 0) {
            const int pos = lbase[ebk[it]] + erk[it];
            staged[pos] = epk[it];
            bkt_of[pos] = (ushort)ebk[it];
        }
    }
    __syncthreads();

    const int total = min(P1E, EE - blockIdx.x * P1E);
    for (int i = t; i < total; i += 256) {
        const int bk = bkt_of[i];
        barr[(size_t)bk * CAP + gbase[bk] + (i - lbase[bk])] = staged[i];
    }
}

// ---------------------------------------------------------------------------
// CSR build pass 2 (scan folded in): one block per bucket (256 rows).
// Bucket prefix computed in-block from cursor[]; row-histogram + LDS scan ->
// rp[]; reorder edges into LDS sorted[]; write csr sequentially.
// ---------------------------------------------------------------------------
__global__ __launch_bounds__(256) void bucket_pass2(
    const int* __restrict__ cursor, const int2* __restrict__ barr,
    int* __restrict__ rp, int2* __restrict__ csr)
{
    __shared__ int tmp[256];
    __shared__ int gbs;
    __shared__ int rowcnt[256];
    __shared__ int rowcur[256];
    __shared__ int2 sorted[CAP];       // 40 KB
    const int b = blockIdx.x;
    const int t = threadIdx.x;

    // gb = sum_{u<b} cursor[u] via tree reduce
    int partial = 0;
    if (t < b)       partial += cursor[t];
    if (t + 256 < b) partial += cursor[t + 256];
    tmp[t] = partial;
    __syncthreads();
    for (int off = 128; off > 0; off >>= 1) {
        if (t < off) tmp[t] += tmp[t + off];
        __syncthreads();
    }
    if (t == 0) gbs = tmp[0];
    __syncthreads();
    const int gb = gbs;
    const int sz = cursor[b];
    const int2* my = barr + (size_t)b * CAP;
    if (b == BKT - 1 && t == 0) rp[NN] = EE;

    rowcnt[t] = 0;
    __syncthreads();
    for (int i = t; i < sz; i += 256)
        atomicAdd(&rowcnt[(my[i].y >> 17) & 255], 1);  // LDS
    __syncthreads();
    const int c = rowcnt[t];
    tmp[t] = c;
    __syncthreads();
    for (int off = 1; off < 256; off <<= 1) {
        const int v = (t >= off) ? tmp[t - off] : 0;
        __syncthreads();
        tmp[t] += v;
        __syncthreads();
    }
    const int excl = tmp[t] - c;
    rowcur[t] = excl;
    const int row = b * 256 + t;
    if (row < NN) rp[row] = gb + excl;
    __syncthreads();
    for (int i = t; i < sz; i += 256) {
        const int2 e = my[i];
        const int rl = (e.y >> 17) & 255;
        const int slot = atomicAdd(&rowcur[rl], 1);    // LDS, returning
        sorted[slot] = make_int2(e.y & 0x1FFFF, e.x);
    }
    __syncthreads();
    for (int i = t; i < sz; i += 256)
        csr[gb + i] = sorted[i];
}

// ---------------------------------------------------------------------------
// SpMM v2 (CSR, bf16 feat): one row per 64-lane wave; 4x 16-lane groups each
// gather a DIFFERENT edge's 256B row (dwordx4/lane). 8 edges in flight per
// iteration; inactive slots use val=0. Epilogue: shfl_xor(16,32) reduce.
// f32 accumulate, bf16 output.  [R8 version: 63.4us; R9 16-edge was worse]
// ---------------------------------------------------------------------------
__global__ __launch_bounds__(256) void spmm_csr_bf16(
    const int* __restrict__ rp, const int2* __restrict__ csr,
    const ushort* __restrict__ featb, ushort* __restrict__ outb)
{
    const int tid  = blockIdx.x * 256 + threadIdx.x;
    const int row  = tid >> 6;
    const int lane = threadIdx.x & 63;
    const int g    = lane >> 4;      // edge slot 0..3
    const int li   = lane & 15;      // 16B segment within row

    const int start = rp[row];
    const int end   = rp[row + 1];

    float acc[8] = {0.f, 0.f, 0.f, 0.f, 0.f, 0.f, 0.f, 0.f};

    for (int base = start; base < end; base += 8) {
        const int p0 = base + g;
        const int p1 = base + 4 + g;
        int2 e0 = make_int2(0, 0), e1 = make_int2(0, 0);
        if (p0 < end) e0 = csr[p0];
        if (p1 < end) e1 = csr[p1];
        const float v0 = __int_as_float(e0.y);   // 0.0f when inactive
        const float v1 = __int_as_float(e1.y);
        const uint4 g0 = *reinterpret_cast<const uint4*>(featb + (size_t)e0.x * 128 + li * 8);
        const uint4 g1 = *reinterpret_cast<const uint4*>(featb + (size_t)e1.x * 128 + li * 8);
        acc[0] = fmaf(v0, bflo(g0.x), acc[0]); acc[1] = fmaf(v0, bfhi(g0.x), acc[1]);
        acc[2] = fmaf(v0, bflo(g0.y), acc[2]); acc[3] = fmaf(v0, bfhi(g0.y), acc[3]);
        acc[4] = fmaf(v0, bflo(g0.z), acc[4]); acc[5] = fmaf(v0, bfhi(g0.z), acc[5]);
        acc[6] = fmaf(v0, bflo(g0.w), acc[6]); acc[7] = fmaf(v0, bfhi(g0.w), acc[7]);
        acc[0] = fmaf(v1, bflo(g1.x), acc[0]); acc[1] = fmaf(v1, bfhi(g1.x), acc[1]);
        acc[2] = fmaf(v1, bflo(g1.y), acc[2]); acc[3] = fmaf(v1, bfhi(g1.y), acc[3]);
        acc[4] = fmaf(v1, bflo(g1.z), acc[4]); acc[5] = fmaf(v1, bfhi(g1.z), acc[5]);
        acc[6] = fmaf(v1, bflo(g1.w), acc[6]); acc[7] = fmaf(v1, bfhi(g1.w), acc[7]);
    }

    #pragma unroll
    for (int i = 0; i < 8; ++i) {
        acc[i] += __shfl_xor(acc[i], 16);
        acc[i] += __shfl_xor(acc[i], 32);
    }

    if (g == 0) {
        uint4 o;
        o.x = ((uint)f2bf(acc[1]) << 16) | (uint)f2bf(acc[0]);
        o.y = ((uint)f2bf(acc[3]) << 16) | (uint)f2bf(acc[2]);
        o.z = ((uint)f2bf(acc[5]) << 16) | (uint)f2bf(acc[4]);
        o.w = ((uint)f2bf(acc[7]) << 16) | (uint)f2bf(acc[6]);
        *reinterpret_cast<uint4*>(outb + (size_t)row * 128 + li * 8) = o;
    }
}

// ---------------------------------------------------------------------------
// GEMM v4: out[N,128] = concat(xb,f1b,f2b)[N,384](bf16) @ Wb[128,384]^T + b
// MFMA 16x16x32_bf16. BM=128, 512 threads = 8 waves. ALL 12 A-fragments
// preloaded before the K loop (HBM latency overlaps W staging + MFMA).
// Only W staged in LDS (XOR-swizzled). C/D: col=lane&15, row=(lane>>4)*4+reg.
// ---------------------------------------------------------------------------
__global__ __launch_bounds__(512) void gemm_mfma(
    const ushort* __restrict__ xb, const ushort* __restrict__ f1b,
    const ushort* __restrict__ f2b, const ushort* __restrict__ Wb,
    const float* __restrict__ b, float* __restrict__ out)
{
    __shared__ ushort Ws[128 * 64];

    const int t    = threadIdx.x;
    const int wave = t >> 6;
    const int lane = t & 63;
    const int lr   = lane & 15;
    const int lg   = lane >> 4;
    const int rbase = blockIdx.x * 128;

    int arow = rbase + wave * 16 + lr;
    if (arow >= NN) arow = NN - 1;          // clamp; stores are guarded

    // preload all A fragments (12 x 16B global loads, issued back-to-back)
    s16x8 a[6][2];
    #pragma unroll
    for (int c = 0; c < 6; ++c) {
        const ushort* src = (c < 2) ? xb : ((c < 4) ? f1b : f2b);
        const int col0 = (c & 1) * 64;
        a[c][0] = *reinterpret_cast<const s16x8*>(src + (size_t)arow * 128 + col0 + lg * 8);
        a[c][1] = *reinterpret_cast<const s16x8*>(src + (size_t)arow * 128 + col0 + 32 + lg * 8);
    }

    f32x4 acc[8];
    #pragma unroll
    for (int j = 0; j < 8; ++j) {
        const float bv = b[j * 16 + lr];
        acc[j] = (f32x4){bv, bv, bv, bv};
    }

    #pragma unroll
    for (int c = 0; c < 6; ++c) {
        const int k0w = c * 64;

        #pragma unroll
        for (int it = 0; it < 2; ++it) {
            const int idx = it * 512 + t;
            const int col = idx >> 3, seg = idx & 7;
            const s16x8 v = *reinterpret_cast<const s16x8*>(Wb + (size_t)col * 384 + k0w + seg * 8);
            *reinterpret_cast<s16x8*>(&Ws[col * 64 + ((seg ^ (col & 7)) * 8)]) = v;
        }
        __syncthreads();

        #pragma unroll
        for (int kk = 0; kk < 2; ++kk) {
            #pragma unroll
            for (int j = 0; j < 8; ++j) {
                const int bcol = j * 16 + lr;
                const int bch  = (kk * 4 + lg) ^ (bcol & 7);
                const s16x8 bf = *reinterpret_cast<const s16x8*>(&Ws[bcol * 64 + bch * 8]);
                acc[j] = __builtin_amdgcn_mfma_f32_16x16x32_bf16(a[c][kk], bf, acc[j], 0, 0, 0);
            }
        }
        __syncthreads();
    }

    #pragma unroll
    for (int j = 0; j < 8; ++j) {
        #pragma unroll
        for (int j2 = 0; j2 < 4; ++j2) {
            const int rg = rbase + wave * 16 + lg * 4 + j2;
            if (rg < NN)
                out[(size_t)rg * 128 + j * 16 + lr] = acc[j][j2];
        }
    }
}

extern "C" void kernel_launch(void* const* d_in, const int* in_sizes, int n_in,
                              void* d_out, int out_size, void* d_ws, size_t ws_size,
                              hipStream_t stream)
{
    const float* x    = (const float*)d_in[0];
    const int*   esrc = (const int*)  d_in[1];
    const int*   edst = (const int*)  d_in[2];
    const float* eval = (const float*)d_in[3];
    const float* W    = (const float*)d_in[4];
    const float* b    = (const float*)d_in[5];
    float* out = (float*)d_out;

    char* ws = (char*)d_ws;
    const size_t FB = (size_t)NN * D * 2;                 // 25,600,000 B
    ushort* xb     = (ushort*)(ws);
    ushort* f1b    = (ushort*)(ws + FB);
    ushort* f2b    = (ushort*)(ws + 2 * FB);
    ushort* Wb     = (ushort*)(ws + 3 * FB);              // 98,304 B
    char*   p      = ws + 3 * FB + 98304;
    int2*   csr    = (int2*)p;               p += (size_t)EE * 8;        // 12.8 MB
    int2*   barr   = (int2*)p;               p += (size_t)BKT * CAP * 8; // 16.0 MB
    int*    cursor = (int*)p;                p += (BKT + 1) * 4;
    int*    rp     = (int*)p;                                            // (NN+1)*4

    hipMemsetAsync(cursor, 0, BKT * sizeof(int), stream);

    cvt_both<<<(XN4 + WN4 + 255) / 256, 256, 0, stream>>>(x, xb, W, Wb);

    bucket_pass1<<<(EE + P1E - 1) / P1E, 256, 0, stream>>>(esrc, edst, eval, cursor, barr);
    bucket_pass2<<<BKT, 256, 0, stream>>>(cursor, barr, rp, csr);

    spmm_csr_bf16<<<NN / 4, 256, 0, stream>>>(rp, csr, xb,  f1b);
    spmm_csr_bf16<<<NN / 4, 256, 0, stream>>>(rp, csr, f1b, f2b);

    gemm_mfma<<<(NN + 127) / 128, 512, 0, stream>>>(xb, f1b, f2b, Wb, b, out);
}